// Round 6
// baseline (3689.190 us; speedup 1.0000x reference)
//
#include <hip/hip_runtime.h>
#include <hip/hip_bf16.h>

#define BATCH 2048
#define FEAT  768
#define NIND  1024
#define NCLS  16

typedef unsigned short u16;
typedef __attribute__((ext_vector_type(8))) __bf16 bf16x8;
typedef __attribute__((ext_vector_type(4))) float f32x4;

static __device__ __forceinline__ unsigned f2bf(float f) {
  unsigned u = __float_as_uint(f);
  unsigned r = ((u >> 16) & 1u) + 0x7FFFu;
  return (u + r) >> 16;                       // RNE bf16 in low 16 bits
}

// pack 8 bf16 (as uint4) scaled by wv[0..7] back to 8 bf16 (uint4)
static __device__ __forceinline__ uint4 scale8(uint4 v, const float* wv) {
  unsigned out[4];
  const unsigned* in = (const unsigned*)&v;
  #pragma unroll
  for (int i = 0; i < 4; ++i) {
    float lo = __uint_as_float((in[i] & 0xFFFFu) << 16) * wv[2*i];
    float hi = __uint_as_float(in[i] & 0xFFFF0000u) * wv[2*i+1];
    __hip_bfloat162 pk = __float22bfloat162_rn(float2{lo, hi});
    out[i] = *(unsigned*)&pk;
  }
  return uint4{out[0], out[1], out[2], out[3]};
}

// K1: phi = sqrt(2/N)*cos(2*(x@W+b)); writes phi [B][N] f32, phiB [B][N] bf16, phiTB [N][B] bf16
__global__ __launch_bounds__(256) void phi_kernel(
    const float* __restrict__ x, const float* __restrict__ rw,
    const float* __restrict__ rb, float* __restrict__ phi,
    u16* __restrict__ phiB, u16* __restrict__ phiTB)
{
  __shared__ float xs[64][17];
  __shared__ float wsh[16][68];
  __shared__ float ts[64][65];
  const int b0 = blockIdx.x * 64, i0 = blockIdx.y * 64;
  const int tid = threadIdx.x;
  const int tr = tid >> 4, tc = tid & 15;
  float acc[4][4] = {};
  for (int k0 = 0; k0 < FEAT; k0 += 16) {
    {
      int bb = tid >> 2, kk = (tid & 3) << 2;
      float4 v = *(const float4*)(x + (size_t)(b0 + bb) * FEAT + k0 + kk);
      xs[bb][kk] = v.x; xs[bb][kk+1] = v.y; xs[bb][kk+2] = v.z; xs[bb][kk+3] = v.w;
      int k2 = tid >> 4, ii = (tid & 15) << 2;
      *(float4*)(&wsh[k2][ii]) = *(const float4*)(rw + (size_t)(k0 + k2) * NIND + i0 + ii);
    }
    __syncthreads();
    #pragma unroll
    for (int q = 0; q < 16; ++q) {
      float a[4];
      #pragma unroll
      for (int r = 0; r < 4; ++r) a[r] = xs[tr*4+r][q];
      float4 b4 = *(const float4*)(&wsh[q][tc*4]);
      float bv[4] = {b4.x, b4.y, b4.z, b4.w};
      #pragma unroll
      for (int r = 0; r < 4; ++r)
        #pragma unroll
        for (int c = 0; c < 4; ++c) acc[r][c] += a[r] * bv[c];
    }
    __syncthreads();
  }
  const float SC = 0.04419417382415922f;   // sqrt(2/1024)
  float4 rb4 = *(const float4*)(rb + i0 + tc*4);
  float rbl[4] = {rb4.x, rb4.y, rb4.z, rb4.w};
  #pragma unroll
  for (int r = 0; r < 4; ++r) {
    float vals[4];
    #pragma unroll
    for (int c = 0; c < 4; ++c) {
      float pr = 2.0f * (acc[r][c] + rbl[c]);
      vals[c] = SC * cosf(pr);
      ts[tr*4+r][tc*4+c] = vals[c];
    }
    float4 o = make_float4(vals[0], vals[1], vals[2], vals[3]);
    *(float4*)(phi + (size_t)(b0 + tr*4 + r) * NIND + i0 + tc*4) = o;
    uint2 ob;
    ob.x = (f2bf(o.x) & 0xFFFFu) | (f2bf(o.y) << 16);
    ob.y = (f2bf(o.z) & 0xFFFFu) | (f2bf(o.w) << 16);
    *(uint2*)(phiB + (size_t)(b0 + tr*4 + r) * NIND + i0 + tc*4) = ob;
  }
  __syncthreads();
  #pragma unroll
  for (int rep = 0; rep < 4; ++rep) {
    int ii = tr*4 + rep;
    int bb2 = tc*4;
    float4 o = make_float4(ts[bb2][ii], ts[bb2+1][ii], ts[bb2+2][ii], ts[bb2+3][ii]);
    uint2 ob;
    ob.x = (f2bf(o.x) & 0xFFFFu) | (f2bf(o.y) << 16);
    ob.y = (f2bf(o.z) & 0xFFFFu) | (f2bf(o.w) << 16);
    *(uint2*)(phiTB + (size_t)(i0 + ii) * BATCH + b0 + bb2) = ob;
  }
}

// K2: tiled logits GEMM + in-block softmax -> sqrtw[k][b] = sqrt(p(1-p))
__global__ __launch_bounds__(256) void logits_kernel(
    const float* __restrict__ phi, const float* __restrict__ bw,
    const float* __restrict__ bbias, float* __restrict__ out,
    float* __restrict__ sqrtw)
{
  __shared__ float ph[64][132];
  __shared__ float bwl[16][132];
  __shared__ float lg[64][17];
  const int b0 = blockIdx.x * 64;
  const int tid = threadIdx.x;
  const int bl = tid & 63, kq = tid >> 6;
  float acc[4] = {};
  for (int kb = 0; kb < NIND; kb += 128) {
    #pragma unroll
    for (int i = 0; i < 8; ++i) {
      int f = i * 256 + tid;
      int row = f >> 5, c4 = (f & 31) << 2;
      *(float4*)(&ph[row][c4]) = *(const float4*)(phi + (size_t)(b0 + row) * NIND + kb + c4);
    }
    #pragma unroll
    for (int i = 0; i < 2; ++i) {
      int f = i * 256 + tid;
      int row = f >> 5, c4 = (f & 31) << 2;
      *(float4*)(&bwl[row][c4]) = *(const float4*)(bw + (size_t)row * NIND + kb + c4);
    }
    __syncthreads();
    #pragma unroll 8
    for (int q = 0; q < 128; q += 4) {
      float4 a = *(const float4*)(&ph[bl][q]);
      #pragma unroll
      for (int j = 0; j < 4; ++j) {
        float4 b4 = *(const float4*)(&bwl[kq*4+j][q]);
        acc[j] += a.x*b4.x + a.y*b4.y + a.z*b4.z + a.w*b4.w;
      }
    }
    __syncthreads();
  }
  #pragma unroll
  for (int j = 0; j < 4; ++j) {
    float v = acc[j] + bbias[kq*4+j];
    lg[bl][kq*4+j] = v;
    out[(size_t)(b0 + bl) * NCLS + kq*4 + j] = v;
  }
  __syncthreads();
  if (tid < 64) {
    float mx = -1e30f;
    #pragma unroll
    for (int k = 0; k < 16; ++k) mx = fmaxf(mx, lg[tid][k]);
    float s = 0.f, ex[16];
    #pragma unroll
    for (int k = 0; k < 16; ++k) { ex[k] = expf(lg[tid][k] - mx); s += ex[k]; }
    float inv = 1.0f / s;
    #pragma unroll
    for (int k = 0; k < 16; ++k) {
      float p = ex[k] * inv;
      sqrtw[(size_t)k * BATCH + b0 + tid] = sqrtf(fmaxf(p * (1.0f - p), 0.f));
    }
  }
}

// K3 v4: MFMA bf16 gram with in-kernel sqrt(w) scaling from phiTB (no phiW buffer).
// C_k = sum_b (sw*phi)_i (sw*phi)_j ; 128x128 tile per (pair, class).
__global__ __launch_bounds__(256) void gram_kernel(
    const u16* __restrict__ phiTB, const float* __restrict__ sqrtw,
    const float* __restrict__ prec, float* __restrict__ P)
{
  __shared__ u16 Als[128 * 64];
  __shared__ u16 Bls[128 * 64];
  int p = blockIdx.x;
  int ti = 0;
  while ((ti + 1) * (ti + 2) / 2 <= p) ++ti;
  int tj = p - ti * (ti + 1) / 2;
  const int k = blockIdx.y;
  const int i0 = ti * 128, j0 = tj * 128;
  const bool diag = (ti == tj);
  const int tid = threadIdx.x;
  const int wid = tid >> 6, lane = tid & 63;
  const int wr = wid >> 1, wc = wid & 1;
  const u16* Ag = phiTB + (size_t)i0 * BATCH;
  const u16* Bg = phiTB + (size_t)j0 * BATCH;
  const float* sw = sqrtw + (size_t)k * BATCH;
  f32x4 acc[4][4];
  #pragma unroll
  for (int m = 0; m < 4; ++m)
    #pragma unroll
    for (int n = 0; n < 4; ++n) acc[m][n] = (f32x4){0.f, 0.f, 0.f, 0.f};
  const int kc8 = tid & 7;
  for (int b0 = 0; b0 < BATCH; b0 += 64) {
    const int bcol = b0 + kc8 * 8;
    float4 w0 = *(const float4*)(sw + bcol);
    float4 w1 = *(const float4*)(sw + bcol + 4);
    float wv[8] = {w0.x, w0.y, w0.z, w0.w, w1.x, w1.y, w1.z, w1.w};
    #pragma unroll
    for (int c = 0; c < 4; ++c) {
      int row = c * 32 + (tid >> 3);
      int idx = (row * 64 + kc8 * 8) ^ ((row & 7) << 3);
      uint4 va = *(const uint4*)(Ag + (size_t)row * BATCH + bcol);
      *(uint4*)(&Als[idx]) = scale8(va, wv);
      if (!diag) {
        uint4 vb = *(const uint4*)(Bg + (size_t)row * BATCH + bcol);
        *(uint4*)(&Bls[idx]) = scale8(vb, wv);
      }
    }
    __syncthreads();
    const u16* Bp = diag ? Als : Bls;
    #pragma unroll
    for (int ks = 0; ks < 2; ++ks) {
      bf16x8 af[4], bfr[4];
      #pragma unroll
      for (int m = 0; m < 4; ++m) {
        int row = wr * 64 + m * 16 + (lane & 15);
        int kb = ks * 32 + (lane >> 4) * 8;
        int idx = (row * 64 + kb) ^ ((row & 7) << 3);
        af[m] = *(const bf16x8*)(&Als[idx]);
      }
      #pragma unroll
      for (int n = 0; n < 4; ++n) {
        int row = wc * 64 + n * 16 + (lane & 15);
        int kb = ks * 32 + (lane >> 4) * 8;
        int idx = (row * 64 + kb) ^ ((row & 7) << 3);
        bfr[n] = *(const bf16x8*)(&Bp[idx]);
      }
      #pragma unroll
      for (int m = 0; m < 4; ++m)
        #pragma unroll
        for (int n = 0; n < 4; ++n)
          acc[m][n] = __builtin_amdgcn_mfma_f32_16x16x32_bf16(af[m], bfr[n], acc[m][n], 0, 0, 0);
    }
    __syncthreads();
  }
  const size_t kb2 = (size_t)k * NIND * NIND;
  #pragma unroll
  for (int m = 0; m < 4; ++m) {
    #pragma unroll
    for (int n = 0; n < 4; ++n) {
      #pragma unroll
      for (int r = 0; r < 4; ++r) {
        int gi = i0 + wr * 64 + m * 16 + (lane >> 4) * 4 + r;
        int gj = j0 + wc * 64 + n * 16 + (lane & 15);
        float v = acc[m][n][r];
        size_t idx = kb2 + (size_t)gi * NIND + gj;
        float pr = prec[idx];
        P[idx] = v + pr;
        if (!diag) {
          size_t idx2 = kb2 + (size_t)gj * NIND + gi;
          P[idx2] = v + pr;
        }
      }
    }
  }
}

// K4 v3: 128x128 diag factor, blocked-32 (wave-synchronous diag, few barriers)
// + per-32-block inverse + doubling to 128-inverse; writes Uf32/Ubf16 diag block.
__global__ __launch_bounds__(1024) void potrf_kernel(
    float* __restrict__ P, float* __restrict__ Uf32, u16* __restrict__ Ubf16, int it)
{
  __shared__ float D[128][129];
  __shared__ float W[128][132];
  __shared__ float sinv[128];
  __shared__ float Tmp[3][32][33];
  const int k = blockIdx.x, tid = threadIdx.x;
  const int wid = tid >> 6, lane = tid & 63;
  const size_t base = (size_t)k * NIND * NIND + (size_t)(it * 128) * NIND + it * 128;
  for (int t = tid; t < 128 * 128; t += 1024)
    D[t >> 7][t & 127] = P[base + (size_t)(t >> 7) * NIND + (t & 127)];
  __syncthreads();
  for (int B = 0; B < 4; ++B) {
    const int b0 = B * 32;
    if (wid == 0) {
      const int r = lane;
      // wave-synchronous 32x32 Cholesky (lanes 0..31 own rows)
      for (int j = 0; j < 32; ++j) {
        float djj = D[b0 + j][b0 + j];
        float s = sqrtf(djj);
        float is = 1.0f / s;
        if (lane == 0) sinv[b0 + j] = is;
        if (r > j && r < 32) {
          float lrj = D[b0 + r][b0 + j] * is;
          D[b0 + r][b0 + j] = lrj;
        }
        __builtin_amdgcn_wave_barrier();
        if (r > j && r < 32) {
          float lrj = D[b0 + r][b0 + j];
          for (int c = j + 1; c <= r; ++c)
            D[b0 + r][b0 + c] -= lrj * D[b0 + c][b0 + j];
        }
        __builtin_amdgcn_wave_barrier();
        if (lane == 0) D[b0 + j][b0 + j] = s;
      }
      __builtin_amdgcn_wave_barrier();
      // W11 = inv(L_BB): column-per-lane forward substitution (no cross-lane deps)
      if (lane < 32) {
        const int c = lane;
        for (int rr = 0; rr < 32; ++rr) {
          float v;
          if (rr < c) v = 0.f;
          else {
            float s2 = 0.f;
            for (int j2 = c; j2 < rr; ++j2) s2 += D[b0 + rr][b0 + j2] * W[b0 + j2][b0 + c];
            v = (((rr == c) ? 1.0f : 0.0f) - s2) * sinv[b0 + rr];
          }
          W[b0 + rr][b0 + c] = v;
        }
      }
    }
    __syncthreads();
    const int nrows = 96 - b0;
    if (nrows > 0) {
      // panel: L21 = A21 * W11^T  (in-place via register staging)
      float pv[3];
      int i = 0;
      for (int t = tid; t < nrows * 32; t += 1024, ++i) {
        int rr = b0 + 32 + (t >> 5), cc = t & 31;
        float s3 = 0.f;
        #pragma unroll
        for (int j = 0; j < 32; ++j) s3 += D[rr][b0 + j] * W[b0 + cc][b0 + j];
        pv[i] = s3;
      }
      __syncthreads();
      i = 0;
      for (int t = tid; t < nrows * 32; t += 1024, ++i) {
        int rr = b0 + 32 + (t >> 5), cc = t & 31;
        D[rr][b0 + cc] = pv[i];
      }
      __syncthreads();
      // trailing syrk: lower triangle rows/cols >= b0+32 (panel cols disjoint from writes)
      for (int t = tid; t < nrows * nrows; t += 1024) {
        int rr = b0 + 32 + t / nrows, cc = b0 + 32 + t % nrows;
        if (cc <= rr) {
          float s4 = 0.f;
          #pragma unroll
          for (int j = 0; j < 32; ++j) s4 += D[rr][b0 + j] * D[cc][b0 + j];
          D[rr][cc] -= s4;
        }
      }
      __syncthreads();
    }
  }
  // doubling within 128: off-diag inverse blocks W_IJ = -W_II * (sum L_IK W_KJ)
  for (int d = 1; d <= 3; ++d) {
    int nb = 4 - d;
    for (int t = tid; t < nb * 1024; t += 1024) {
      int bi = t >> 10, rc = t & 1023, r = rc >> 5, c = rc & 31;
      int J = bi, I = J + d;
      float s = 0.f;
      for (int K = J; K < I; ++K)
        #pragma unroll 8
        for (int j = 0; j < 32; ++j)
          s += D[I*32 + r][K*32 + j] * W[K*32 + j][J*32 + c];
      Tmp[bi][r][c] = s;
    }
    __syncthreads();
    for (int t = tid; t < nb * 1024; t += 1024) {
      int bi = t >> 10, rc = t & 1023, r = rc >> 5, c = rc & 31;
      int J = bi, I = J + d;
      float s = 0.f;
      for (int j = 0; j <= r; ++j)
        s += W[I*32 + r][I*32 + j] * Tmp[bi][j][c];
      W[I*32 + r][J*32 + c] = -s;
    }
    __syncthreads();
  }
  for (int t = tid; t < 128 * 128; t += 1024) {
    int r = t >> 7, c = t & 127;
    float v = (c <= r) ? W[r][c] : 0.f;
    size_t uo = base + (size_t)r * NIND + c;
    Uf32[uo] = v;
    Ubf16[uo] = (u16)f2bf(v);
  }
}

// K5 v2: fused trailing update. Block (a,b): recompute La,Lb = A(panel)*W^T in LDS,
// then P(a,b) -= La*Lb^T. Panels in P are NOT modified (panels_kernel does that later).
__global__ __launch_bounds__(256) void update_kernel(
    float* __restrict__ P, const float* __restrict__ Uf32, int it)
{
  __shared__ float As[64][17];
  __shared__ float Ws[128][17];
  __shared__ float La[64][68];
  __shared__ float LbT[128][68];
  int p = blockIdx.x;
  int a = (int)((sqrtf(8.f * p + 1.f) - 1.f) * 0.5f);
  while ((a + 1) * (a + 2) / 2 <= p) ++a;
  while (a * (a + 1) / 2 > p) --a;
  int b = p - a * (a + 1) / 2;
  const int k = blockIdx.y;
  const size_t pb = (size_t)k * NIND * NIND;
  const int jb = it * 128;
  const int r0 = jb + 128 + a * 64, c0 = jb + 128 + b * 64;
  const float* W = Uf32 + pb + (size_t)jb * NIND + jb;   // inv diag block, ld NIND
  const int tid = threadIdx.x, tr = tid >> 4, tc = tid & 15;
  const bool diag = (a == b);
  for (int pass = 0; pass < 2; ++pass) {
    if (pass == 1 && diag) break;
    const int rr0 = pass ? c0 : r0;
    float acc[4][8] = {};
    for (int j0 = 0; j0 < 128; j0 += 16) {
      {
        int rr = tid >> 2, jj = (tid & 3) << 2;
        *(float4*)(&As[rr][jj]) = *(const float4*)(P + pb + (size_t)(rr0 + rr) * NIND + jb + j0 + jj);
        #pragma unroll
        for (int t2 = 0; t2 < 2; ++t2) {
          int f = tid + t2 * 256;
          int r2 = f >> 2, j2 = (f & 3) << 2;
          *(float4*)(&Ws[r2][j2]) = *(const float4*)(W + (size_t)r2 * NIND + j0 + j2);
        }
      }
      __syncthreads();
      #pragma unroll
      for (int q = 0; q < 16; ++q) {
        float av[4];
        #pragma unroll
        for (int r = 0; r < 4; ++r) av[r] = As[tr*4+r][q];
        #pragma unroll
        for (int c = 0; c < 8; ++c) {
          float lv = Ws[tc*8+c][q];
          #pragma unroll
          for (int r = 0; r < 4; ++r) acc[r][c] += av[r] * lv;
        }
      }
      __syncthreads();
    }
    #pragma unroll
    for (int r = 0; r < 4; ++r) {
      #pragma unroll
      for (int c = 0; c < 8; ++c) {
        int orow = tr*4 + r, ocol = tc*8 + c;
        if (pass == 0) {
          La[orow][ocol] = acc[r][c];
          if (diag) LbT[ocol][orow] = acc[r][c];
        } else {
          LbT[ocol][orow] = acc[r][c];
        }
      }
    }
    __syncthreads();
  }
  float acc2[4][4] = {};
  #pragma unroll 4
  for (int j = 0; j < 128; ++j) {
    float av[4];
    #pragma unroll
    for (int r = 0; r < 4; ++r) av[r] = La[tr*4+r][j];
    float4 bv = *(const float4*)(&LbT[j][tc*4]);
    #pragma unroll
    for (int r = 0; r < 4; ++r) {
      acc2[r][0] += av[r] * bv.x; acc2[r][1] += av[r] * bv.y;
      acc2[r][2] += av[r] * bv.z; acc2[r][3] += av[r] * bv.w;
    }
  }
  #pragma unroll
  for (int r = 0; r < 4; ++r) {
    float* dst = P + pb + (size_t)(r0 + tr*4 + r) * NIND + c0 + tc*4;
    float4 cur = *(float4*)dst;
    cur.x -= acc2[r][0]; cur.y -= acc2[r][1]; cur.z -= acc2[r][2]; cur.w -= acc2[r][3];
    *(float4*)dst = cur;
  }
}

// K5b: materialize all L-panels in P (in-place): L = A * W_it^T, one block per (it, 64-row tile)
__global__ __launch_bounds__(256) void panels_kernel(
    float* __restrict__ P, const float* __restrict__ Uf32)
{
  __shared__ float As[64][17];
  __shared__ float Ws[128][17];
  int bx = blockIdx.x;
  int it = 0;
  while (bx >= 14 - 2 * it) { bx -= 14 - 2 * it; ++it; }
  const int k = blockIdx.y;
  const size_t pb = (size_t)k * NIND * NIND;
  const int jb = it * 128;
  const int r0 = jb + 128 + bx * 64;
  const float* W = Uf32 + pb + (size_t)jb * NIND + jb;
  const int tid = threadIdx.x, tr = tid >> 4, tc = tid & 15;
  float acc[4][8] = {};
  for (int j0 = 0; j0 < 128; j0 += 16) {
    {
      int rr = tid >> 2, jj = (tid & 3) << 2;
      *(float4*)(&As[rr][jj]) = *(const float4*)(P + pb + (size_t)(r0 + rr) * NIND + jb + j0 + jj);
      #pragma unroll
      for (int t2 = 0; t2 < 2; ++t2) {
        int f = tid + t2 * 256;
        int r2 = f >> 2, j2 = (f & 3) << 2;
        *(float4*)(&Ws[r2][j2]) = *(const float4*)(W + (size_t)r2 * NIND + j0 + j2);
      }
    }
    __syncthreads();
    #pragma unroll
    for (int q = 0; q < 16; ++q) {
      float av[4];
      #pragma unroll
      for (int r = 0; r < 4; ++r) av[r] = As[tr*4+r][q];
      #pragma unroll
      for (int c = 0; c < 8; ++c) {
        float lv = Ws[tc*8+c][q];
        #pragma unroll
        for (int r = 0; r < 4; ++r) acc[r][c] += av[r] * lv;
      }
    }
    __syncthreads();
  }
  #pragma unroll
  for (int r = 0; r < 4; ++r) {
    #pragma unroll
    for (int c4 = 0; c4 < 8; c4 += 4) {
      float4 o = make_float4(acc[r][c4], acc[r][c4+1], acc[r][c4+2], acc[r][c4+3]);
      *(float4*)(P + pb + (size_t)(r0 + tr*4 + r) * NIND + jb + tc*8 + c4) = o;
    }
  }
}

// K8: generic 128x128-tile f32 GEMM for the doubling triangular inverse (6 modes).
__global__ __launch_bounds__(256) void dgemm_kernel(
    const float* __restrict__ P, const float* __restrict__ Uin,
    float* __restrict__ Uf32, u16* __restrict__ Ubf16,
    float* __restrict__ Tsc, int mode)
{
  const int k = blockIdx.y;
  const int bx = blockIdx.x;
  const size_t ub = (size_t)k * NIND * NIND;
  const float* A = nullptr; const float* B = nullptr;
  float* Cf = nullptr; u16* Cb = nullptr; float* Ct = nullptr;
  int lda = 0, ldb = 0, ldc = 0, ldt = 0, K = 0;
  bool toU = false;
  if (mode == 0) {
    int p = bx;
    A = Uin + ub + (size_t)((2*p+1)*128) * NIND + (2*p+1)*128; lda = NIND;
    B = P + ub + (size_t)((2*p+1)*128) * NIND + (2*p)*128; ldb = NIND;
    Ct = Tsc + ((size_t)k*4 + p) * 16384; ldt = 128; K = 128;
  } else if (mode == 1) {
    int p = bx;
    A = Tsc + ((size_t)k*4 + p) * 16384; lda = 128;
    B = Uin + ub + (size_t)((2*p)*128) * NIND + (2*p)*128; ldb = NIND;
    Cf = Uf32 + ub + (size_t)((2*p+1)*128) * NIND + (2*p)*128;
    Cb = Ubf16 + ub + (size_t)((2*p+1)*128) * NIND + (2*p)*128;
    ldc = NIND; K = 128; toU = true;
  } else if (mode == 2) {
    int q = bx >> 2, r = (bx >> 1) & 1, c = bx & 1;
    A = Uin + ub + (size_t)((4*q+2+r)*128) * NIND + (4*q+2)*128; lda = NIND;
    B = P + ub + (size_t)((4*q+2)*128) * NIND + (4*q+c)*128; ldb = NIND;
    Ct = Tsc + ((size_t)k*2 + q) * 65536 + (size_t)r*128*256 + c*128; ldt = 256; K = 256;
  } else if (mode == 3) {
    int q = bx >> 2, r = (bx >> 1) & 1, c = bx & 1;
    A = Tsc + ((size_t)k*2 + q) * 65536 + (size_t)r*128*256; lda = 256;
    B = Uin + ub + (size_t)((4*q)*128) * NIND + (4*q)*128; ldb = NIND;
    Cf = Uf32 + ub + (size_t)((4*q+2+r)*128) * NIND + (4*q+c)*128;
    Cb = Ubf16 + ub + (size_t)((4*q+2+r)*128) * NIND + (4*q+c)*128;
    ldc = NIND; K = 256; toU = true;
  } else if (mode == 4) {
    int r = bx >> 2, c = bx & 3;
    A = Uin + ub + (size_t)((4+r)*128) * NIND + 512; lda = NIND;
    B = P + ub + (size_t)512 * NIND + c*128; ldb = NIND;
    Ct = Tsc + (size_t)k * 262144 + (size_t)r*128*512 + c*128; ldt = 512; K = 512;
  } else {
    int r = bx >> 2, c = bx & 3;
    A = Tsc + (size_t)k * 262144 + (size_t)r*128*512; lda = 512;
    B = Uin + ub + c*128; ldb = NIND;
    Cf = Uf32 + ub + (size_t)((4+r)*128) * NIND + c*128;
    Cb = Ubf16 + ub + (size_t)((4+r)*128) * NIND + c*128;
    ldc = NIND; K = 512; toU = true;
  }
  __shared__ float As[128][17];
  __shared__ float Bs[16][132];
  const int tid = threadIdx.x, tr = tid >> 4, tc = tid & 15;
  float acc[8][8] = {};
  for (int kb = 0; kb < K; kb += 16) {
    #pragma unroll
    for (int t = 0; t < 2; ++t) {
      int f = t * 256 + tid;
      int r2 = f >> 2, q4 = (f & 3) << 2;
      *(float4*)(&As[r2][q4]) = *(const float4*)(A + (size_t)r2 * lda + kb + q4);
    }
    #pragma unroll
    for (int t = 0; t < 2; ++t) {
      int f = t * 256 + tid;
      int q2 = f >> 5, c4 = (f & 31) << 2;
      *(float4*)(&Bs[q2][c4]) = *(const float4*)(B + (size_t)(kb + q2) * ldb + c4);
    }
    __syncthreads();
    #pragma unroll
    for (int q = 0; q < 16; ++q) {
      float a[8], b[8];
      #pragma unroll
      for (int r = 0; r < 8; ++r) a[r] = As[tr*8+r][q];
      #pragma unroll
      for (int c = 0; c < 8; ++c) b[c] = Bs[q][tc*8+c];
      #pragma unroll
      for (int r = 0; r < 8; ++r)
        #pragma unroll
        for (int c = 0; c < 8; ++c) acc[r][c] += a[r] * b[c];
    }
    __syncthreads();
  }
  if (toU) {
    #pragma unroll
    for (int r = 0; r < 8; ++r) {
      #pragma unroll
      for (int c = 0; c < 8; ++c) {
        float v = -acc[r][c];
        size_t idx = (size_t)(tr*8+r) * ldc + tc*8+c;
        Cf[idx] = v;
        Cb[idx] = (u16)f2bf(v);
      }
    }
  } else {
    #pragma unroll
    for (int r = 0; r < 8; ++r) {
      #pragma unroll
      for (int c = 0; c < 8; c += 4) {
        float4 o = make_float4(acc[r][c], acc[r][c+1], acc[r][c+2], acc[r][c+3]);
        *(float4*)(Ct + (size_t)(tr*8+r) * ldt + tc*8+c) = o;
      }
    }
  }
}

// K9: Y = U * phi^T (triangular K-limit), fused column square-sums -> partial[It][k][b]
__global__ __launch_bounds__(256) void ygemm_kernel(
    const u16* __restrict__ Ubf16, const u16* __restrict__ phiB,
    float* __restrict__ partial)
{
  __shared__ u16 Als[128 * 64];
  __shared__ u16 Bls[128 * 64];
  __shared__ float sq_lds[128][9];
  const int b0 = blockIdx.x * 128;
  const int It = blockIdx.y;
  const int k = blockIdx.z;
  const int tid = threadIdx.x;
  const int wid = tid >> 6, lane = tid & 63;
  const int wr = wid >> 1, wc = wid & 1;
  const u16* Ag = Ubf16 + (size_t)k * NIND * NIND + (size_t)(It * 128) * NIND;
  const u16* Bg = phiB + (size_t)b0 * NIND;
  f32x4 acc[4][4];
  #pragma unroll
  for (int m = 0; m < 4; ++m)
    #pragma unroll
    for (int n = 0; n < 4; ++n) acc[m][n] = (f32x4){0.f, 0.f, 0.f, 0.f};
  const int Kmax = (It + 1) * 128;
  for (int j0 = 0; j0 < Kmax; j0 += 64) {
    #pragma unroll
    for (int c = 0; c < 4; ++c) {
      int f = c * 256 + tid;
      int row = f >> 3, kc8 = f & 7;
      uint4 va = *(const uint4*)(Ag + (size_t)row * NIND + j0 + kc8 * 8);
      uint4 vb = *(const uint4*)(Bg + (size_t)row * NIND + j0 + kc8 * 8);
      int idx = (row * 64 + kc8 * 8) ^ ((row & 7) << 3);
      *(uint4*)(&Als[idx]) = va;
      *(uint4*)(&Bls[idx]) = vb;
    }
    __syncthreads();
    #pragma unroll
    for (int ks = 0; ks < 2; ++ks) {
      bf16x8 af[4], bfr[4];
      #pragma unroll
      for (int m = 0; m < 4; ++m) {
        int row = wr * 64 + m * 16 + (lane & 15);
        int kb = ks * 32 + (lane >> 4) * 8;
        int idx = (row * 64 + kb) ^ ((row & 7) << 3);
        af[m] = *(const bf16x8*)(&Als[idx]);
      }
      #pragma unroll
      for (int n = 0; n < 4; ++n) {
        int row = wc * 64 + n * 16 + (lane & 15);
        int kb = ks * 32 + (lane >> 4) * 8;
        int idx = (row * 64 + kb) ^ ((row & 7) << 3);
        bfr[n] = *(const bf16x8*)(&Bls[idx]);
      }
      #pragma unroll
      for (int m = 0; m < 4; ++m)
        #pragma unroll
        for (int n = 0; n < 4; ++n)
          acc[m][n] = __builtin_amdgcn_mfma_f32_16x16x32_bf16(af[m], bfr[n], acc[m][n], 0, 0, 0);
    }
    __syncthreads();
  }
  #pragma unroll
  for (int n = 0; n < 4; ++n) {
    float s = 0.f;
    #pragma unroll
    for (int m = 0; m < 4; ++m)
      #pragma unroll
      for (int r = 0; r < 4; ++r) { float v = acc[m][n][r]; s += v * v; }
    int col = wc * 64 + n * 16 + (lane & 15);
    sq_lds[col][wr * 4 + (lane >> 4)] = s;
  }
  __syncthreads();
  if (tid < 128) {
    float s = 0.f;
    #pragma unroll
    for (int t = 0; t < 8; ++t) s += sq_lds[tid][t];
    partial[((size_t)It * NCLS + k) * BATCH + b0 + tid] = s;
  }
}

// K10: out variances[b][k] = sum_It partial[It][k][b]
__global__ __launch_bounds__(256) void reduce_kernel(
    const float* __restrict__ partial, float* __restrict__ out)
{
  int t = blockIdx.x * 256 + threadIdx.x;
  int k = t >> 11, b = t & 2047;
  float s = 0.f;
  #pragma unroll
  for (int It = 0; It < 8; ++It)
    s += partial[((size_t)It * NCLS + k) * BATCH + b];
  out[(size_t)BATCH * NCLS + (size_t)b * NCLS + k] = s;
}

extern "C" void kernel_launch(void* const* d_in, const int* in_sizes, int n_in,
                              void* d_out, int out_size, void* d_ws, size_t ws_size,
                              hipStream_t stream)
{
  (void)in_sizes; (void)n_in; (void)ws_size;
  const float* x   = (const float*)d_in[0];
  const float* rw  = (const float*)d_in[1];
  const float* rb  = (const float*)d_in[2];
  const float* bw  = (const float*)d_in[3];
  const float* bb  = (const float*)d_in[4];
  const float* prc = (const float*)d_in[5];
  float* out = (float*)d_out;
  char* ws = (char*)d_ws;
  size_t off = 0;
  auto alloc = [&](size_t bytes) -> void* {
    void* p = ws + off;
    off = (off + bytes + 255) & ~(size_t)255;
    return p;
  };
  float* phi   = (float*)alloc((size_t)BATCH * NIND * 4);
  u16*   phiB  = (u16*)  alloc((size_t)BATCH * NIND * 2);
  u16*   phiTB = (u16*)  alloc((size_t)NIND * BATCH * 2);
  float* sqw   = (float*)alloc((size_t)NCLS * BATCH * 4);
  float* P     = (float*)alloc((size_t)NCLS * NIND * NIND * 4);
  float* Uf32  = (float*)alloc((size_t)NCLS * NIND * NIND * 4);
  u16*   Ubf16 = (u16*)  alloc((size_t)NCLS * NIND * NIND * 2);
  float* partial = (float*)alloc((size_t)8 * NCLS * BATCH * 4);
  float* Tsc   = (float*)alloc((size_t)NCLS * 262144 * 4);   // 16MB

  hipMemsetAsync(d_out, 0, (size_t)out_size * sizeof(float), stream);
  hipMemsetAsync(Uf32, 0, (size_t)NCLS * NIND * NIND * 4, stream);
  phi_kernel<<<dim3(BATCH/64, NIND/64), 256, 0, stream>>>(x, rw, rb, phi, phiB, phiTB);
  logits_kernel<<<dim3(BATCH/64), 256, 0, stream>>>(phi, bw, bb, out, sqw);
  gram_kernel<<<dim3(36, NCLS), 256, 0, stream>>>(phiTB, sqw, prc, P);
  for (int it = 0; it < 8; ++it) {
    potrf_kernel<<<dim3(NCLS), 1024, 0, stream>>>(P, Uf32, Ubf16, it);
    if (it < 7) {
      int n64 = 14 - 2 * it;
      update_kernel<<<dim3(n64 * (n64 + 1) / 2, NCLS), 256, 0, stream>>>(P, Uf32, it);
    }
  }
  panels_kernel<<<dim3(56, NCLS), 256, 0, stream>>>(P, Uf32);
  dgemm_kernel<<<dim3(4,  NCLS), 256, 0, stream>>>(P, Uf32, Uf32, Ubf16, Tsc, 0);
  dgemm_kernel<<<dim3(4,  NCLS), 256, 0, stream>>>(P, Uf32, Uf32, Ubf16, Tsc, 1);
  dgemm_kernel<<<dim3(8,  NCLS), 256, 0, stream>>>(P, Uf32, Uf32, Ubf16, Tsc, 2);
  dgemm_kernel<<<dim3(8,  NCLS), 256, 0, stream>>>(P, Uf32, Uf32, Ubf16, Tsc, 3);
  dgemm_kernel<<<dim3(16, NCLS), 256, 0, stream>>>(P, Uf32, Uf32, Ubf16, Tsc, 4);
  dgemm_kernel<<<dim3(16, NCLS), 256, 0, stream>>>(P, Uf32, Uf32, Ubf16, Tsc, 5);
  ygemm_kernel<<<dim3(BATCH/128, 8, NCLS), 256, 0, stream>>>(Ubf16, phiB, partial);
  reduce_kernel<<<dim3(128), 256, 0, stream>>>(partial, out);
}

// Round 7
// 3070.678 us; speedup vs baseline: 1.2014x; 1.2014x over previous
//
#include <hip/hip_runtime.h>
#include <hip/hip_bf16.h>

#define BATCH 2048
#define FEAT  768
#define NIND  1024
#define NCLS  16

typedef unsigned short u16;
typedef __attribute__((ext_vector_type(8))) __bf16 bf16x8;
typedef __attribute__((ext_vector_type(4))) float f32x4;

static __device__ __forceinline__ unsigned f2bf(float f) {
  unsigned u = __float_as_uint(f);
  unsigned r = ((u >> 16) & 1u) + 0x7FFFu;
  return (u + r) >> 16;                       // RNE bf16 in low 16 bits
}

// pack 8 bf16 (as uint4) scaled by wv[0..7] back to 8 bf16 (uint4)
static __device__ __forceinline__ uint4 scale8(uint4 v, const float* wv) {
  unsigned out[4];
  const unsigned* in = (const unsigned*)&v;
  #pragma unroll
  for (int i = 0; i < 4; ++i) {
    float lo = __uint_as_float((in[i] & 0xFFFFu) << 16) * wv[2*i];
    float hi = __uint_as_float(in[i] & 0xFFFF0000u) * wv[2*i+1];
    __hip_bfloat162 pk = __float22bfloat162_rn(float2{lo, hi});
    out[i] = *(unsigned*)&pk;
  }
  return uint4{out[0], out[1], out[2], out[3]};
}

// K1: phi = sqrt(2/N)*cos(2*(x@W+b)); writes phi [B][N] f32, phiB [B][N] bf16, phiTB [N][B] bf16
__global__ __launch_bounds__(256) void phi_kernel(
    const float* __restrict__ x, const float* __restrict__ rw,
    const float* __restrict__ rb, float* __restrict__ phi,
    u16* __restrict__ phiB, u16* __restrict__ phiTB)
{
  __shared__ float xs[64][17];
  __shared__ float wsh[16][68];
  __shared__ float ts[64][65];
  const int b0 = blockIdx.x * 64, i0 = blockIdx.y * 64;
  const int tid = threadIdx.x;
  const int tr = tid >> 4, tc = tid & 15;
  float acc[4][4] = {};
  for (int k0 = 0; k0 < FEAT; k0 += 16) {
    {
      int bb = tid >> 2, kk = (tid & 3) << 2;
      float4 v = *(const float4*)(x + (size_t)(b0 + bb) * FEAT + k0 + kk);
      xs[bb][kk] = v.x; xs[bb][kk+1] = v.y; xs[bb][kk+2] = v.z; xs[bb][kk+3] = v.w;
      int k2 = tid >> 4, ii = (tid & 15) << 2;
      *(float4*)(&wsh[k2][ii]) = *(const float4*)(rw + (size_t)(k0 + k2) * NIND + i0 + ii);
    }
    __syncthreads();
    #pragma unroll
    for (int q = 0; q < 16; ++q) {
      float a[4];
      #pragma unroll
      for (int r = 0; r < 4; ++r) a[r] = xs[tr*4+r][q];
      float4 b4 = *(const float4*)(&wsh[q][tc*4]);
      float bv[4] = {b4.x, b4.y, b4.z, b4.w};
      #pragma unroll
      for (int r = 0; r < 4; ++r)
        #pragma unroll
        for (int c = 0; c < 4; ++c) acc[r][c] += a[r] * bv[c];
    }
    __syncthreads();
  }
  const float SC = 0.04419417382415922f;   // sqrt(2/1024)
  float4 rb4 = *(const float4*)(rb + i0 + tc*4);
  float rbl[4] = {rb4.x, rb4.y, rb4.z, rb4.w};
  #pragma unroll
  for (int r = 0; r < 4; ++r) {
    float vals[4];
    #pragma unroll
    for (int c = 0; c < 4; ++c) {
      float pr = 2.0f * (acc[r][c] + rbl[c]);
      vals[c] = SC * cosf(pr);
      ts[tr*4+r][tc*4+c] = vals[c];
    }
    float4 o = make_float4(vals[0], vals[1], vals[2], vals[3]);
    *(float4*)(phi + (size_t)(b0 + tr*4 + r) * NIND + i0 + tc*4) = o;
    uint2 ob;
    ob.x = (f2bf(o.x) & 0xFFFFu) | (f2bf(o.y) << 16);
    ob.y = (f2bf(o.z) & 0xFFFFu) | (f2bf(o.w) << 16);
    *(uint2*)(phiB + (size_t)(b0 + tr*4 + r) * NIND + i0 + tc*4) = ob;
  }
  __syncthreads();
  #pragma unroll
  for (int rep = 0; rep < 4; ++rep) {
    int ii = tr*4 + rep;
    int bb2 = tc*4;
    float4 o = make_float4(ts[bb2][ii], ts[bb2+1][ii], ts[bb2+2][ii], ts[bb2+3][ii]);
    uint2 ob;
    ob.x = (f2bf(o.x) & 0xFFFFu) | (f2bf(o.y) << 16);
    ob.y = (f2bf(o.z) & 0xFFFFu) | (f2bf(o.w) << 16);
    *(uint2*)(phiTB + (size_t)(i0 + ii) * BATCH + b0 + bb2) = ob;
  }
}

// K2: tiled logits GEMM + in-block softmax -> sqrtw[k][b] = sqrt(p(1-p))
__global__ __launch_bounds__(256) void logits_kernel(
    const float* __restrict__ phi, const float* __restrict__ bw,
    const float* __restrict__ bbias, float* __restrict__ out,
    float* __restrict__ sqrtw)
{
  __shared__ float ph[64][132];
  __shared__ float bwl[16][132];
  __shared__ float lg[64][17];
  const int b0 = blockIdx.x * 64;
  const int tid = threadIdx.x;
  const int bl = tid & 63, kq = tid >> 6;
  float acc[4] = {};
  for (int kb = 0; kb < NIND; kb += 128) {
    #pragma unroll
    for (int i = 0; i < 8; ++i) {
      int f = i * 256 + tid;
      int row = f >> 5, c4 = (f & 31) << 2;
      *(float4*)(&ph[row][c4]) = *(const float4*)(phi + (size_t)(b0 + row) * NIND + kb + c4);
    }
    #pragma unroll
    for (int i = 0; i < 2; ++i) {
      int f = i * 256 + tid;
      int row = f >> 5, c4 = (f & 31) << 2;
      *(float4*)(&bwl[row][c4]) = *(const float4*)(bw + (size_t)row * NIND + kb + c4);
    }
    __syncthreads();
    #pragma unroll 8
    for (int q = 0; q < 128; q += 4) {
      float4 a = *(const float4*)(&ph[bl][q]);
      #pragma unroll
      for (int j = 0; j < 4; ++j) {
        float4 b4 = *(const float4*)(&bwl[kq*4+j][q]);
        acc[j] += a.x*b4.x + a.y*b4.y + a.z*b4.z + a.w*b4.w;
      }
    }
    __syncthreads();
  }
  #pragma unroll
  for (int j = 0; j < 4; ++j) {
    float v = acc[j] + bbias[kq*4+j];
    lg[bl][kq*4+j] = v;
    out[(size_t)(b0 + bl) * NCLS + kq*4 + j] = v;
  }
  __syncthreads();
  if (tid < 64) {
    float mx = -1e30f;
    #pragma unroll
    for (int k = 0; k < 16; ++k) mx = fmaxf(mx, lg[tid][k]);
    float s = 0.f, ex[16];
    #pragma unroll
    for (int k = 0; k < 16; ++k) { ex[k] = expf(lg[tid][k] - mx); s += ex[k]; }
    float inv = 1.0f / s;
    #pragma unroll
    for (int k = 0; k < 16; ++k) {
      float p = ex[k] * inv;
      sqrtw[(size_t)k * BATCH + b0 + tid] = sqrtf(fmaxf(p * (1.0f - p), 0.f));
    }
  }
}

// K3 v4: MFMA bf16 gram with in-kernel sqrt(w) scaling from phiTB (no phiW buffer).
__global__ __launch_bounds__(256) void gram_kernel(
    const u16* __restrict__ phiTB, const float* __restrict__ sqrtw,
    const float* __restrict__ prec, float* __restrict__ P)
{
  __shared__ u16 Als[128 * 64];
  __shared__ u16 Bls[128 * 64];
  int p = blockIdx.x;
  int ti = 0;
  while ((ti + 1) * (ti + 2) / 2 <= p) ++ti;
  int tj = p - ti * (ti + 1) / 2;
  const int k = blockIdx.y;
  const int i0 = ti * 128, j0 = tj * 128;
  const bool diag = (ti == tj);
  const int tid = threadIdx.x;
  const int wid = tid >> 6, lane = tid & 63;
  const int wr = wid >> 1, wc = wid & 1;
  const u16* Ag = phiTB + (size_t)i0 * BATCH;
  const u16* Bg = phiTB + (size_t)j0 * BATCH;
  const float* sw = sqrtw + (size_t)k * BATCH;
  f32x4 acc[4][4];
  #pragma unroll
  for (int m = 0; m < 4; ++m)
    #pragma unroll
    for (int n = 0; n < 4; ++n) acc[m][n] = (f32x4){0.f, 0.f, 0.f, 0.f};
  const int kc8 = tid & 7;
  for (int b0 = 0; b0 < BATCH; b0 += 64) {
    const int bcol = b0 + kc8 * 8;
    float4 w0 = *(const float4*)(sw + bcol);
    float4 w1 = *(const float4*)(sw + bcol + 4);
    float wv[8] = {w0.x, w0.y, w0.z, w0.w, w1.x, w1.y, w1.z, w1.w};
    #pragma unroll
    for (int c = 0; c < 4; ++c) {
      int row = c * 32 + (tid >> 3);
      int idx = (row * 64 + kc8 * 8) ^ ((row & 7) << 3);
      uint4 va = *(const uint4*)(Ag + (size_t)row * BATCH + bcol);
      *(uint4*)(&Als[idx]) = scale8(va, wv);
      if (!diag) {
        uint4 vb = *(const uint4*)(Bg + (size_t)row * BATCH + bcol);
        *(uint4*)(&Bls[idx]) = scale8(vb, wv);
      }
    }
    __syncthreads();
    const u16* Bp = diag ? Als : Bls;
    #pragma unroll
    for (int ks = 0; ks < 2; ++ks) {
      bf16x8 af[4], bfr[4];
      #pragma unroll
      for (int m = 0; m < 4; ++m) {
        int row = wr * 64 + m * 16 + (lane & 15);
        int kb = ks * 32 + (lane >> 4) * 8;
        int idx = (row * 64 + kb) ^ ((row & 7) << 3);
        af[m] = *(const bf16x8*)(&Als[idx]);
      }
      #pragma unroll
      for (int n = 0; n < 4; ++n) {
        int row = wc * 64 + n * 16 + (lane & 15);
        int kb = ks * 32 + (lane >> 4) * 8;
        int idx = (row * 64 + kb) ^ ((row & 7) << 3);
        bfr[n] = *(const bf16x8*)(&Bp[idx]);
      }
      #pragma unroll
      for (int m = 0; m < 4; ++m)
        #pragma unroll
        for (int n = 0; n < 4; ++n)
          acc[m][n] = __builtin_amdgcn_mfma_f32_16x16x32_bf16(af[m], bfr[n], acc[m][n], 0, 0, 0);
    }
    __syncthreads();
  }
  const size_t kb2 = (size_t)k * NIND * NIND;
  #pragma unroll
  for (int m = 0; m < 4; ++m) {
    #pragma unroll
    for (int n = 0; n < 4; ++n) {
      #pragma unroll
      for (int r = 0; r < 4; ++r) {
        int gi = i0 + wr * 64 + m * 16 + (lane >> 4) * 4 + r;
        int gj = j0 + wc * 64 + n * 16 + (lane & 15);
        float v = acc[m][n][r];
        size_t idx = kb2 + (size_t)gi * NIND + gj;
        float pr = prec[idx];
        P[idx] = v + pr;
        if (!diag) {
          size_t idx2 = kb2 + (size_t)gj * NIND + gi;
          P[idx2] = v + pr;
        }
      }
    }
  }
}

// K4 v3: 128x128 diag factor, blocked-32 (wave-synchronous diag, few barriers)
// + per-32-block inverse + doubling to 128-inverse; writes Uf32/Ubf16 diag block.
__global__ __launch_bounds__(1024) void potrf_kernel(
    float* __restrict__ P, float* __restrict__ Uf32, u16* __restrict__ Ubf16, int it)
{
  __shared__ float D[128][129];
  __shared__ float W[128][132];
  __shared__ float sinv[128];
  __shared__ float Tmp[3][32][33];
  const int k = blockIdx.x, tid = threadIdx.x;
  const int wid = tid >> 6, lane = tid & 63;
  const size_t base = (size_t)k * NIND * NIND + (size_t)(it * 128) * NIND + it * 128;
  for (int t = tid; t < 128 * 128; t += 1024)
    D[t >> 7][t & 127] = P[base + (size_t)(t >> 7) * NIND + (t & 127)];
  __syncthreads();
  for (int B = 0; B < 4; ++B) {
    const int b0 = B * 32;
    if (wid == 0) {
      const int r = lane;
      for (int j = 0; j < 32; ++j) {
        float djj = D[b0 + j][b0 + j];
        float s = sqrtf(djj);
        float is = 1.0f / s;
        if (lane == 0) sinv[b0 + j] = is;
        if (r > j && r < 32) {
          float lrj = D[b0 + r][b0 + j] * is;
          D[b0 + r][b0 + j] = lrj;
        }
        __builtin_amdgcn_wave_barrier();
        if (r > j && r < 32) {
          float lrj = D[b0 + r][b0 + j];
          for (int c = j + 1; c <= r; ++c)
            D[b0 + r][b0 + c] -= lrj * D[b0 + c][b0 + j];
        }
        __builtin_amdgcn_wave_barrier();
        if (lane == 0) D[b0 + j][b0 + j] = s;
      }
      __builtin_amdgcn_wave_barrier();
      if (lane < 32) {
        const int c = lane;
        for (int rr = 0; rr < 32; ++rr) {
          float v;
          if (rr < c) v = 0.f;
          else {
            float s2 = 0.f;
            for (int j2 = c; j2 < rr; ++j2) s2 += D[b0 + rr][b0 + j2] * W[b0 + j2][b0 + c];
            v = (((rr == c) ? 1.0f : 0.0f) - s2) * sinv[b0 + rr];
          }
          W[b0 + rr][b0 + c] = v;
        }
      }
    }
    __syncthreads();
    const int nrows = 96 - b0;
    if (nrows > 0) {
      float pv[3];
      int i = 0;
      for (int t = tid; t < nrows * 32; t += 1024, ++i) {
        int rr = b0 + 32 + (t >> 5), cc = t & 31;
        float s3 = 0.f;
        #pragma unroll
        for (int j = 0; j < 32; ++j) s3 += D[rr][b0 + j] * W[b0 + cc][b0 + j];
        pv[i] = s3;
      }
      __syncthreads();
      i = 0;
      for (int t = tid; t < nrows * 32; t += 1024, ++i) {
        int rr = b0 + 32 + (t >> 5), cc = t & 31;
        D[rr][b0 + cc] = pv[i];
      }
      __syncthreads();
      for (int t = tid; t < nrows * nrows; t += 1024) {
        int rr = b0 + 32 + t / nrows, cc = b0 + 32 + t % nrows;
        if (cc <= rr) {
          float s4 = 0.f;
          #pragma unroll
          for (int j = 0; j < 32; ++j) s4 += D[rr][b0 + j] * D[cc][b0 + j];
          D[rr][cc] -= s4;
        }
      }
      __syncthreads();
    }
  }
  for (int d = 1; d <= 3; ++d) {
    int nb = 4 - d;
    for (int t = tid; t < nb * 1024; t += 1024) {
      int bi = t >> 10, rc = t & 1023, r = rc >> 5, c = rc & 31;
      int J = bi, I = J + d;
      float s = 0.f;
      for (int K = J; K < I; ++K)
        #pragma unroll 8
        for (int j = 0; j < 32; ++j)
          s += D[I*32 + r][K*32 + j] * W[K*32 + j][J*32 + c];
      Tmp[bi][r][c] = s;
    }
    __syncthreads();
    for (int t = tid; t < nb * 1024; t += 1024) {
      int bi = t >> 10, rc = t & 1023, r = rc >> 5, c = rc & 31;
      int J = bi, I = J + d;
      float s = 0.f;
      for (int j = 0; j <= r; ++j)
        s += W[I*32 + r][I*32 + j] * Tmp[bi][j][c];
      W[I*32 + r][J*32 + c] = -s;
    }
    __syncthreads();
  }
  for (int t = tid; t < 128 * 128; t += 1024) {
    int r = t >> 7, c = t & 127;
    float v = (c <= r) ? W[r][c] : 0.f;
    size_t uo = base + (size_t)r * NIND + c;
    Uf32[uo] = v;
    Ubf16[uo] = (u16)f2bf(v);
  }
}

// K5: panel trsm: L21 = A21 * Winv^T (in place in P). Winv = Uf32 diag block (ld NIND).
__global__ __launch_bounds__(256) void trsm_kernel(
    float* __restrict__ P, const float* __restrict__ Uf32, int it)
{
  __shared__ float As[64][17];
  __shared__ float Ls[128][17];
  const int k = blockIdx.y;
  const int r0 = (it + 1) * 128 + blockIdx.x * 64;
  const int jb = it * 128;
  const int tid = threadIdx.x, tr = tid >> 4, tc = tid & 15;
  const size_t pb = (size_t)k * NIND * NIND;
  const float* invb = Uf32 + pb + (size_t)jb * NIND + jb;   // ld NIND
  float acc[4][8] = {};
  for (int j0 = 0; j0 < 128; j0 += 16) {
    {
      int rr = tid >> 2, jj = (tid & 3) << 2;
      float4 v = *(const float4*)(P + pb + (size_t)(r0 + rr) * NIND + jb + j0 + jj);
      As[rr][jj] = v.x; As[rr][jj+1] = v.y; As[rr][jj+2] = v.z; As[rr][jj+3] = v.w;
      #pragma unroll
      for (int t = 0; t < 2; ++t) {
        int f = tid + t * 256;
        int r2 = f >> 2, j2 = (f & 3) << 2;
        float4 u = *(const float4*)(invb + (size_t)r2 * NIND + j0 + j2);
        Ls[r2][j2] = u.x; Ls[r2][j2+1] = u.y; Ls[r2][j2+2] = u.z; Ls[r2][j2+3] = u.w;
      }
    }
    __syncthreads();
    #pragma unroll
    for (int qq = 0; qq < 16; ++qq) {
      float a[4];
      #pragma unroll
      for (int r = 0; r < 4; ++r) a[r] = As[tr*4+r][qq];
      #pragma unroll
      for (int c = 0; c < 8; ++c) {
        float lv = Ls[tc*8+c][qq];
        #pragma unroll
        for (int r = 0; r < 4; ++r) acc[r][c] += a[r] * lv;
      }
    }
    __syncthreads();
  }
  #pragma unroll
  for (int r = 0; r < 4; ++r) {
    #pragma unroll
    for (int c0 = 0; c0 < 8; c0 += 4) {
      float4 o = make_float4(acc[r][c0], acc[r][c0+1], acc[r][c0+2], acc[r][c0+3]);
      *(float4*)(P + pb + (size_t)(r0 + tr*4 + r) * NIND + jb + tc*8 + c0) = o;
    }
  }
}

// K6: trailing update A22 -= L21 L21^T (lower 64-tile pairs)
__global__ __launch_bounds__(256) void syrk_kernel(float* __restrict__ P, int it)
{
  __shared__ float Pa[64][17];
  __shared__ float Pb[64][17];
  int p = blockIdx.x;
  int a = (int)((sqrtf(8.f * p + 1.f) - 1.f) * 0.5f);
  while ((a + 1) * (a + 2) / 2 <= p) ++a;
  while (a * (a + 1) / 2 > p) --a;
  int b = p - a * (a + 1) / 2;
  const int tbase = (it + 1) * 2;
  const int r0 = (tbase + a) * 64, c0 = (tbase + b) * 64;
  const int jb = it * 128;
  const int k = blockIdx.y;
  const size_t pb = (size_t)k * NIND * NIND;
  const int tid = threadIdx.x, tr = tid >> 4, tc = tid & 15;
  float acc[4][4] = {};
  for (int j0 = 0; j0 < 128; j0 += 16) {
    int rr = tid >> 2, jj = (tid & 3) << 2;
    float4 v = *(const float4*)(P + pb + (size_t)(r0 + rr) * NIND + jb + j0 + jj);
    Pa[rr][jj] = v.x; Pa[rr][jj+1] = v.y; Pa[rr][jj+2] = v.z; Pa[rr][jj+3] = v.w;
    float4 u = *(const float4*)(P + pb + (size_t)(c0 + rr) * NIND + jb + j0 + jj);
    Pb[rr][jj] = u.x; Pb[rr][jj+1] = u.y; Pb[rr][jj+2] = u.z; Pb[rr][jj+3] = u.w;
    __syncthreads();
    #pragma unroll
    for (int qq = 0; qq < 16; ++qq) {
      float av[4], bv[4];
      #pragma unroll
      for (int r = 0; r < 4; ++r) av[r] = Pa[tr*4+r][qq];
      #pragma unroll
      for (int c = 0; c < 4; ++c) bv[c] = Pb[tc*4+c][qq];
      #pragma unroll
      for (int r = 0; r < 4; ++r)
        #pragma unroll
        for (int c = 0; c < 4; ++c) acc[r][c] += av[r] * bv[c];
    }
    __syncthreads();
  }
  #pragma unroll
  for (int r = 0; r < 4; ++r) {
    float* dst = P + pb + (size_t)(r0 + tr*4 + r) * NIND + c0 + tc*4;
    float4 cur = *(float4*)dst;
    cur.x -= acc[r][0]; cur.y -= acc[r][1]; cur.z -= acc[r][2]; cur.w -= acc[r][3];
    *(float4*)dst = cur;
  }
}

// K8: generic 128x128-tile f32 GEMM for the doubling triangular inverse (6 modes).
__global__ __launch_bounds__(256) void dgemm_kernel(
    const float* __restrict__ P, const float* __restrict__ Uin,
    float* __restrict__ Uf32, u16* __restrict__ Ubf16,
    float* __restrict__ Tsc, int mode)
{
  const int k = blockIdx.y;
  const int bx = blockIdx.x;
  const size_t ub = (size_t)k * NIND * NIND;
  const float* A = nullptr; const float* B = nullptr;
  float* Cf = nullptr; u16* Cb = nullptr; float* Ct = nullptr;
  int lda = 0, ldb = 0, ldc = 0, ldt = 0, K = 0;
  bool toU = false;
  if (mode == 0) {
    int p = bx;
    A = Uin + ub + (size_t)((2*p+1)*128) * NIND + (2*p+1)*128; lda = NIND;
    B = P + ub + (size_t)((2*p+1)*128) * NIND + (2*p)*128; ldb = NIND;
    Ct = Tsc + ((size_t)k*4 + p) * 16384; ldt = 128; K = 128;
  } else if (mode == 1) {
    int p = bx;
    A = Tsc + ((size_t)k*4 + p) * 16384; lda = 128;
    B = Uin + ub + (size_t)((2*p)*128) * NIND + (2*p)*128; ldb = NIND;
    Cf = Uf32 + ub + (size_t)((2*p+1)*128) * NIND + (2*p)*128;
    Cb = Ubf16 + ub + (size_t)((2*p+1)*128) * NIND + (2*p)*128;
    ldc = NIND; K = 128; toU = true;
  } else if (mode == 2) {
    int q = bx >> 2, r = (bx >> 1) & 1, c = bx & 1;
    A = Uin + ub + (size_t)((4*q+2+r)*128) * NIND + (4*q+2)*128; lda = NIND;
    B = P + ub + (size_t)((4*q+2)*128) * NIND + (4*q+c)*128; ldb = NIND;
    Ct = Tsc + ((size_t)k*2 + q) * 65536 + (size_t)r*128*256 + c*128; ldt = 256; K = 256;
  } else if (mode == 3) {
    int q = bx >> 2, r = (bx >> 1) & 1, c = bx & 1;
    A = Tsc + ((size_t)k*2 + q) * 65536 + (size_t)r*128*256; lda = 256;
    B = Uin + ub + (size_t)((4*q)*128) * NIND + (4*q)*128; ldb = NIND;
    Cf = Uf32 + ub + (size_t)((4*q+2+r)*128) * NIND + (4*q+c)*128;
    Cb = Ubf16 + ub + (size_t)((4*q+2+r)*128) * NIND + (4*q+c)*128;
    ldc = NIND; K = 256; toU = true;
  } else if (mode == 4) {
    int r = bx >> 2, c = bx & 3;
    A = Uin + ub + (size_t)((4+r)*128) * NIND + 512; lda = NIND;
    B = P + ub + (size_t)512 * NIND + c*128; ldb = NIND;
    Ct = Tsc + (size_t)k * 262144 + (size_t)r*128*512 + c*128; ldt = 512; K = 512;
  } else {
    int r = bx >> 2, c = bx & 3;
    A = Tsc + (size_t)k * 262144 + (size_t)r*128*512; lda = 512;
    B = Uin + ub + c*128; ldb = NIND;
    Cf = Uf32 + ub + (size_t)((4+r)*128) * NIND + c*128;
    Cb = Ubf16 + ub + (size_t)((4+r)*128) * NIND + c*128;
    ldc = NIND; K = 512; toU = true;
  }
  __shared__ float As[128][17];
  __shared__ float Bs[16][132];
  const int tid = threadIdx.x, tr = tid >> 4, tc = tid & 15;
  float acc[8][8] = {};
  for (int kb = 0; kb < K; kb += 16) {
    #pragma unroll
    for (int t = 0; t < 2; ++t) {
      int f = t * 256 + tid;
      int r2 = f >> 2, q4 = (f & 3) << 2;
      *(float4*)(&As[r2][q4]) = *(const float4*)(A + (size_t)r2 * lda + kb + q4);
    }
    #pragma unroll
    for (int t = 0; t < 2; ++t) {
      int f = t * 256 + tid;
      int q2 = f >> 5, c4 = (f & 31) << 2;
      *(float4*)(&Bs[q2][c4]) = *(const float4*)(B + (size_t)(kb + q2) * ldb + c4);
    }
    __syncthreads();
    #pragma unroll
    for (int q = 0; q < 16; ++q) {
      float a[8], b[8];
      #pragma unroll
      for (int r = 0; r < 8; ++r) a[r] = As[tr*8+r][q];
      #pragma unroll
      for (int c = 0; c < 8; ++c) b[c] = Bs[q][tc*8+c];
      #pragma unroll
      for (int r = 0; r < 8; ++r)
        #pragma unroll
        for (int c = 0; c < 8; ++c) acc[r][c] += a[r] * b[c];
    }
    __syncthreads();
  }
  if (toU) {
    #pragma unroll
    for (int r = 0; r < 8; ++r) {
      #pragma unroll
      for (int c = 0; c < 8; ++c) {
        float v = -acc[r][c];
        size_t idx = (size_t)(tr*8+r) * ldc + tc*8+c;
        Cf[idx] = v;
        Cb[idx] = (u16)f2bf(v);
      }
    }
  } else {
    #pragma unroll
    for (int r = 0; r < 8; ++r) {
      #pragma unroll
      for (int c = 0; c < 8; c += 4) {
        float4 o = make_float4(acc[r][c], acc[r][c+1], acc[r][c+2], acc[r][c+3]);
        *(float4*)(Ct + (size_t)(tr*8+r) * ldt + tc*8+c) = o;
      }
    }
  }
}

// K9: Y = U * phi^T (triangular K-limit), fused column square-sums -> partial[It][k][b]
__global__ __launch_bounds__(256) void ygemm_kernel(
    const u16* __restrict__ Ubf16, const u16* __restrict__ phiB,
    float* __restrict__ partial)
{
  __shared__ u16 Als[128 * 64];
  __shared__ u16 Bls[128 * 64];
  __shared__ float sq_lds[128][9];
  const int b0 = blockIdx.x * 128;
  const int It = blockIdx.y;
  const int k = blockIdx.z;
  const int tid = threadIdx.x;
  const int wid = tid >> 6, lane = tid & 63;
  const int wr = wid >> 1, wc = wid & 1;
  const u16* Ag = Ubf16 + (size_t)k * NIND * NIND + (size_t)(It * 128) * NIND;
  const u16* Bg = phiB + (size_t)b0 * NIND;
  f32x4 acc[4][4];
  #pragma unroll
  for (int m = 0; m < 4; ++m)
    #pragma unroll
    for (int n = 0; n < 4; ++n) acc[m][n] = (f32x4){0.f, 0.f, 0.f, 0.f};
  const int Kmax = (It + 1) * 128;
  for (int j0 = 0; j0 < Kmax; j0 += 64) {
    #pragma unroll
    for (int c = 0; c < 4; ++c) {
      int f = c * 256 + tid;
      int row = f >> 3, kc8 = f & 7;
      uint4 va = *(const uint4*)(Ag + (size_t)row * NIND + j0 + kc8 * 8);
      uint4 vb = *(const uint4*)(Bg + (size_t)row * NIND + j0 + kc8 * 8);
      int idx = (row * 64 + kc8 * 8) ^ ((row & 7) << 3);
      *(uint4*)(&Als[idx]) = va;
      *(uint4*)(&Bls[idx]) = vb;
    }
    __syncthreads();
    #pragma unroll
    for (int ks = 0; ks < 2; ++ks) {
      bf16x8 af[4], bfr[4];
      #pragma unroll
      for (int m = 0; m < 4; ++m) {
        int row = wr * 64 + m * 16 + (lane & 15);
        int kb = ks * 32 + (lane >> 4) * 8;
        int idx = (row * 64 + kb) ^ ((row & 7) << 3);
        af[m] = *(const bf16x8*)(&Als[idx]);
      }
      #pragma unroll
      for (int n = 0; n < 4; ++n) {
        int row = wc * 64 + n * 16 + (lane & 15);
        int kb = ks * 32 + (lane >> 4) * 8;
        int idx = (row * 64 + kb) ^ ((row & 7) << 3);
        bfr[n] = *(const bf16x8*)(&Bls[idx]);
      }
      #pragma unroll
      for (int m = 0; m < 4; ++m)
        #pragma unroll
        for (int n = 0; n < 4; ++n)
          acc[m][n] = __builtin_amdgcn_mfma_f32_16x16x32_bf16(af[m], bfr[n], acc[m][n], 0, 0, 0);
    }
    __syncthreads();
  }
  #pragma unroll
  for (int n = 0; n < 4; ++n) {
    float s = 0.f;
    #pragma unroll
    for (int m = 0; m < 4; ++m)
      #pragma unroll
      for (int r = 0; r < 4; ++r) { float v = acc[m][n][r]; s += v * v; }
    int col = wc * 64 + n * 16 + (lane & 15);
    sq_lds[col][wr * 4 + (lane >> 4)] = s;
  }
  __syncthreads();
  if (tid < 128) {
    float s = 0.f;
    #pragma unroll
    for (int t = 0; t < 8; ++t) s += sq_lds[tid][t];
    partial[((size_t)It * NCLS + k) * BATCH + b0 + tid] = s;
  }
}

// K10: out variances[b][k] = sum_It partial[It][k][b]
__global__ __launch_bounds__(256) void reduce_kernel(
    const float* __restrict__ partial, float* __restrict__ out)
{
  int t = blockIdx.x * 256 + threadIdx.x;
  int k = t >> 11, b = t & 2047;
  float s = 0.f;
  #pragma unroll
  for (int It = 0; It < 8; ++It)
    s += partial[((size_t)It * NCLS + k) * BATCH + b];
  out[(size_t)BATCH * NCLS + (size_t)b * NCLS + k] = s;
}

extern "C" void kernel_launch(void* const* d_in, const int* in_sizes, int n_in,
                              void* d_out, int out_size, void* d_ws, size_t ws_size,
                              hipStream_t stream)
{
  (void)in_sizes; (void)n_in; (void)ws_size;
  const float* x   = (const float*)d_in[0];
  const float* rw  = (const float*)d_in[1];
  const float* rb  = (const float*)d_in[2];
  const float* bw  = (const float*)d_in[3];
  const float* bb  = (const float*)d_in[4];
  const float* prc = (const float*)d_in[5];
  float* out = (float*)d_out;
  char* ws = (char*)d_ws;
  size_t off = 0;
  auto alloc = [&](size_t bytes) -> void* {
    void* p = ws + off;
    off = (off + bytes + 255) & ~(size_t)255;
    return p;
  };
  float* phi   = (float*)alloc((size_t)BATCH * NIND * 4);
  u16*   phiB  = (u16*)  alloc((size_t)BATCH * NIND * 2);
  u16*   phiTB = (u16*)  alloc((size_t)NIND * BATCH * 2);
  float* sqw   = (float*)alloc((size_t)NCLS * BATCH * 4);
  float* P     = (float*)alloc((size_t)NCLS * NIND * NIND * 4);
  float* Uf32  = (float*)alloc((size_t)NCLS * NIND * NIND * 4);
  u16*   Ubf16 = (u16*)  alloc((size_t)NCLS * NIND * NIND * 2);
  float* partial = (float*)alloc((size_t)8 * NCLS * BATCH * 4);
  float* Tsc   = (float*)alloc((size_t)NCLS * 262144 * 4);   // 16MB

  hipMemsetAsync(d_out, 0, (size_t)out_size * sizeof(float), stream);
  hipMemsetAsync(Uf32, 0, (size_t)NCLS * NIND * NIND * 4, stream);
  phi_kernel<<<dim3(BATCH/64, NIND/64), 256, 0, stream>>>(x, rw, rb, phi, phiB, phiTB);
  logits_kernel<<<dim3(BATCH/64), 256, 0, stream>>>(phi, bw, bb, out, sqw);
  gram_kernel<<<dim3(36, NCLS), 256, 0, stream>>>(phiTB, sqw, prc, P);
  for (int it = 0; it < 8; ++it) {
    potrf_kernel<<<dim3(NCLS), 1024, 0, stream>>>(P, Uf32, Ubf16, it);
    if (it < 7) {
      trsm_kernel<<<dim3((7 - it) * 2, NCLS), 256, 0, stream>>>(P, Uf32, it);
      int n64 = 14 - 2 * it;
      syrk_kernel<<<dim3(n64 * (n64 + 1) / 2, NCLS), 256, 0, stream>>>(P, it);
    }
  }
  dgemm_kernel<<<dim3(4,  NCLS), 256, 0, stream>>>(P, Uf32, Uf32, Ubf16, Tsc, 0);
  dgemm_kernel<<<dim3(4,  NCLS), 256, 0, stream>>>(P, Uf32, Uf32, Ubf16, Tsc, 1);
  dgemm_kernel<<<dim3(8,  NCLS), 256, 0, stream>>>(P, Uf32, Uf32, Ubf16, Tsc, 2);
  dgemm_kernel<<<dim3(8,  NCLS), 256, 0, stream>>>(P, Uf32, Uf32, Ubf16, Tsc, 3);
  dgemm_kernel<<<dim3(16, NCLS), 256, 0, stream>>>(P, Uf32, Uf32, Ubf16, Tsc, 4);
  dgemm_kernel<<<dim3(16, NCLS), 256, 0, stream>>>(P, Uf32, Uf32, Ubf16, Tsc, 5);
  ygemm_kernel<<<dim3(BATCH/128, 8, NCLS), 256, 0, stream>>>(Ubf16, phiB, partial);
  reduce_kernel<<<dim3(128), 256, 0, stream>>>(partial, out);
}

// Round 9
// 926.012 us; speedup vs baseline: 3.9840x; 3.3160x over previous
//
#include <hip/hip_runtime.h>
#include <hip/hip_bf16.h>

#define BATCH 2048
#define FEAT  768
#define NIND  1024
#define NCLS  16

typedef unsigned short u16;
typedef __attribute__((ext_vector_type(8))) __bf16 bf16x8;
typedef __attribute__((ext_vector_type(4))) float f32x4;

static __device__ __forceinline__ unsigned f2bf(float f) {
  unsigned u = __float_as_uint(f);
  unsigned r = ((u >> 16) & 1u) + 0x7FFFu;
  return (u + r) >> 16;                       // RNE bf16 in low 16 bits
}
static __device__ __forceinline__ float bflo(unsigned x) {
  return __uint_as_float((x & 0xFFFFu) << 16);
}
static __device__ __forceinline__ float bfhi(unsigned x) {
  return __uint_as_float(x & 0xFFFF0000u);
}

// pack 8 bf16 (as uint4) scaled by wv[0..7] back to 8 bf16 (uint4)
static __device__ __forceinline__ uint4 scale8(uint4 v, const float* wv) {
  unsigned out[4];
  const unsigned* in = (const unsigned*)&v;
  #pragma unroll
  for (int i = 0; i < 4; ++i) {
    float lo = bflo(in[i]) * wv[2*i];
    float hi = bfhi(in[i]) * wv[2*i+1];
    __hip_bfloat162 pk = __float22bfloat162_rn(float2{lo, hi});
    out[i] = *(unsigned*)&pk;
  }
  return uint4{out[0], out[1], out[2], out[3]};
}

// K1: phi = sqrt(2/N)*cos(2*(x@W+b)); writes phi [B][N] f32, phiB [B][N] bf16, phiTB [N][B] bf16
__global__ __launch_bounds__(256) void phi_kernel(
    const float* __restrict__ x, const float* __restrict__ rw,
    const float* __restrict__ rb, float* __restrict__ phi,
    u16* __restrict__ phiB, u16* __restrict__ phiTB)
{
  __shared__ float xs[64][17];
  __shared__ float wsh[16][68];
  __shared__ float ts[64][65];
  const int b0 = blockIdx.x * 64, i0 = blockIdx.y * 64;
  const int tid = threadIdx.x;
  const int tr = tid >> 4, tc = tid & 15;
  float acc[4][4] = {};
  for (int k0 = 0; k0 < FEAT; k0 += 16) {
    {
      int bb = tid >> 2, kk = (tid & 3) << 2;
      float4 v = *(const float4*)(x + (size_t)(b0 + bb) * FEAT + k0 + kk);
      xs[bb][kk] = v.x; xs[bb][kk+1] = v.y; xs[bb][kk+2] = v.z; xs[bb][kk+3] = v.w;
      int k2 = tid >> 4, ii = (tid & 15) << 2;
      *(float4*)(&wsh[k2][ii]) = *(const float4*)(rw + (size_t)(k0 + k2) * NIND + i0 + ii);
    }
    __syncthreads();
    #pragma unroll
    for (int q = 0; q < 16; ++q) {
      float a[4];
      #pragma unroll
      for (int r = 0; r < 4; ++r) a[r] = xs[tr*4+r][q];
      float4 b4 = *(const float4*)(&wsh[q][tc*4]);
      float bv[4] = {b4.x, b4.y, b4.z, b4.w};
      #pragma unroll
      for (int r = 0; r < 4; ++r)
        #pragma unroll
        for (int c = 0; c < 4; ++c) acc[r][c] += a[r] * bv[c];
    }
    __syncthreads();
  }
  const float SC = 0.04419417382415922f;   // sqrt(2/1024)
  float4 rb4 = *(const float4*)(rb + i0 + tc*4);
  float rbl[4] = {rb4.x, rb4.y, rb4.z, rb4.w};
  #pragma unroll
  for (int r = 0; r < 4; ++r) {
    float vals[4];
    #pragma unroll
    for (int c = 0; c < 4; ++c) {
      float pr = 2.0f * (acc[r][c] + rbl[c]);
      vals[c] = SC * cosf(pr);
      ts[tr*4+r][tc*4+c] = vals[c];
    }
    float4 o = make_float4(vals[0], vals[1], vals[2], vals[3]);
    *(float4*)(phi + (size_t)(b0 + tr*4 + r) * NIND + i0 + tc*4) = o;
    uint2 ob;
    ob.x = (f2bf(o.x) & 0xFFFFu) | (f2bf(o.y) << 16);
    ob.y = (f2bf(o.z) & 0xFFFFu) | (f2bf(o.w) << 16);
    *(uint2*)(phiB + (size_t)(b0 + tr*4 + r) * NIND + i0 + tc*4) = ob;
  }
  __syncthreads();
  #pragma unroll
  for (int rep = 0; rep < 4; ++rep) {
    int ii = tr*4 + rep;
    int bb2 = tc*4;
    float4 o = make_float4(ts[bb2][ii], ts[bb2+1][ii], ts[bb2+2][ii], ts[bb2+3][ii]);
    uint2 ob;
    ob.x = (f2bf(o.x) & 0xFFFFu) | (f2bf(o.y) << 16);
    ob.y = (f2bf(o.z) & 0xFFFFu) | (f2bf(o.w) << 16);
    *(uint2*)(phiTB + (size_t)(i0 + ii) * BATCH + b0 + bb2) = ob;
  }
}

// K2: tiled logits GEMM + in-block softmax -> sqrtw[k][b] = sqrt(p(1-p))
__global__ __launch_bounds__(256) void logits_kernel(
    const float* __restrict__ phi, const float* __restrict__ bw,
    const float* __restrict__ bbias, float* __restrict__ out,
    float* __restrict__ sqrtw)
{
  __shared__ float ph[64][132];
  __shared__ float bwl[16][132];
  __shared__ float lg[64][17];
  const int b0 = blockIdx.x * 64;
  const int tid = threadIdx.x;
  const int bl = tid & 63, kq = tid >> 6;
  float acc[4] = {};
  for (int kb = 0; kb < NIND; kb += 128) {
    #pragma unroll
    for (int i = 0; i < 8; ++i) {
      int f = i * 256 + tid;
      int row = f >> 5, c4 = (f & 31) << 2;
      *(float4*)(&ph[row][c4]) = *(const float4*)(phi + (size_t)(b0 + row) * NIND + kb + c4);
    }
    #pragma unroll
    for (int i = 0; i < 2; ++i) {
      int f = i * 256 + tid;
      int row = f >> 5, c4 = (f & 31) << 2;
      *(float4*)(&bwl[row][c4]) = *(const float4*)(bw + (size_t)row * NIND + kb + c4);
    }
    __syncthreads();
    #pragma unroll 8
    for (int q = 0; q < 128; q += 4) {
      float4 a = *(const float4*)(&ph[bl][q]);
      #pragma unroll
      for (int j = 0; j < 4; ++j) {
        float4 b4 = *(const float4*)(&bwl[kq*4+j][q]);
        acc[j] += a.x*b4.x + a.y*b4.y + a.z*b4.z + a.w*b4.w;
      }
    }
    __syncthreads();
  }
  #pragma unroll
  for (int j = 0; j < 4; ++j) {
    float v = acc[j] + bbias[kq*4+j];
    lg[bl][kq*4+j] = v;
    out[(size_t)(b0 + bl) * NCLS + kq*4 + j] = v;
  }
  __syncthreads();
  if (tid < 64) {
    float mx = -1e30f;
    #pragma unroll
    for (int k = 0; k < 16; ++k) mx = fmaxf(mx, lg[tid][k]);
    float s = 0.f, ex[16];
    #pragma unroll
    for (int k = 0; k < 16; ++k) { ex[k] = expf(lg[tid][k] - mx); s += ex[k]; }
    float inv = 1.0f / s;
    #pragma unroll
    for (int k = 0; k < 16; ++k) {
      float p = ex[k] * inv;
      sqrtw[(size_t)k * BATCH + b0 + tid] = sqrtf(fmaxf(p * (1.0f - p), 0.f));
    }
  }
}

// K3: MFMA bf16 gram -> Pb bf16 (P = prec + sum_b (sw*phi)_i (sw*phi)_j), symmetric
__global__ __launch_bounds__(256) void gram_kernel(
    const u16* __restrict__ phiTB, const float* __restrict__ sqrtw,
    const float* __restrict__ prec, u16* __restrict__ Pb)
{
  __shared__ u16 Als[128 * 64];
  __shared__ u16 Bls[128 * 64];
  int p = blockIdx.x;
  int ti = 0;
  while ((ti + 1) * (ti + 2) / 2 <= p) ++ti;
  int tj = p - ti * (ti + 1) / 2;
  const int k = blockIdx.y;
  const int i0 = ti * 128, j0 = tj * 128;
  const bool diag = (ti == tj);
  const int tid = threadIdx.x;
  const int wid = tid >> 6, lane = tid & 63;
  const int wr = wid >> 1, wc = wid & 1;
  const u16* Ag = phiTB + (size_t)i0 * BATCH;
  const u16* Bg = phiTB + (size_t)j0 * BATCH;
  const float* sw = sqrtw + (size_t)k * BATCH;
  f32x4 acc[4][4];
  #pragma unroll
  for (int m = 0; m < 4; ++m)
    #pragma unroll
    for (int n = 0; n < 4; ++n) acc[m][n] = (f32x4){0.f, 0.f, 0.f, 0.f};
  const int kc8 = tid & 7;
  for (int b0 = 0; b0 < BATCH; b0 += 64) {
    const int bcol = b0 + kc8 * 8;
    float4 w0 = *(const float4*)(sw + bcol);
    float4 w1 = *(const float4*)(sw + bcol + 4);
    float wv[8] = {w0.x, w0.y, w0.z, w0.w, w1.x, w1.y, w1.z, w1.w};
    #pragma unroll
    for (int c = 0; c < 4; ++c) {
      int row = c * 32 + (tid >> 3);
      int idx = (row * 64 + kc8 * 8) ^ ((row & 7) << 3);
      uint4 va = *(const uint4*)(Ag + (size_t)row * BATCH + bcol);
      *(uint4*)(&Als[idx]) = scale8(va, wv);
      if (!diag) {
        uint4 vb = *(const uint4*)(Bg + (size_t)row * BATCH + bcol);
        *(uint4*)(&Bls[idx]) = scale8(vb, wv);
      }
    }
    __syncthreads();
    const u16* Bp = diag ? Als : Bls;
    #pragma unroll
    for (int ks = 0; ks < 2; ++ks) {
      bf16x8 af[4], bfr[4];
      #pragma unroll
      for (int m = 0; m < 4; ++m) {
        int row = wr * 64 + m * 16 + (lane & 15);
        int kb = ks * 32 + (lane >> 4) * 8;
        int idx = (row * 64 + kb) ^ ((row & 7) << 3);
        af[m] = *(const bf16x8*)(&Als[idx]);
      }
      #pragma unroll
      for (int n = 0; n < 4; ++n) {
        int row = wc * 64 + n * 16 + (lane & 15);
        int kb = ks * 32 + (lane >> 4) * 8;
        int idx = (row * 64 + kb) ^ ((row & 7) << 3);
        bfr[n] = *(const bf16x8*)(&Bp[idx]);
      }
      #pragma unroll
      for (int m = 0; m < 4; ++m)
        #pragma unroll
        for (int n = 0; n < 4; ++n)
          acc[m][n] = __builtin_amdgcn_mfma_f32_16x16x32_bf16(af[m], bfr[n], acc[m][n], 0, 0, 0);
    }
    __syncthreads();
  }
  const size_t kb2 = (size_t)k * NIND * NIND;
  #pragma unroll
  for (int m = 0; m < 4; ++m) {
    #pragma unroll
    for (int n = 0; n < 4; ++n) {
      #pragma unroll
      for (int r = 0; r < 4; ++r) {
        int gi = i0 + wr * 64 + m * 16 + (lane >> 4) * 4 + r;
        int gj = j0 + wc * 64 + n * 16 + (lane & 15);
        size_t idx = kb2 + (size_t)gi * NIND + gj;
        float v = acc[m][n][r] + prec[idx];
        u16 bv = (u16)f2bf(v);
        Pb[idx] = bv;
        if (!diag) Pb[kb2 + (size_t)gj * NIND + gi] = bv;
      }
    }
  }
}

// K4: Gershgorin bound per class: gmax[k] = max_i sum_j |P_ij| (certified >= lambda_max)
__global__ __launch_bounds__(256) void gersh_kernel(
    const u16* __restrict__ Pb, unsigned* __restrict__ gmax)
{
  __shared__ float psum[64][17];
  const int k = blockIdx.y, rbk = blockIdx.x;   // grid (16, NCLS); 64 rows per block
  const int tid = threadIdx.x;
  const size_t mb = (size_t)k * NIND * NIND;
  #pragma unroll
  for (int p = 0; p < 4; ++p) {
    int rl = p * 16 + (tid >> 4);
    int row = rbk * 64 + rl;
    int ch = tid & 15;
    float s = 0.f;
    const u16* base = Pb + mb + (size_t)row * NIND + ch * 64;
    #pragma unroll
    for (int c8 = 0; c8 < 8; ++c8) {
      uint4 u = *(const uint4*)(base + c8 * 8);
      const unsigned* uu = (const unsigned*)&u;
      #pragma unroll
      for (int q = 0; q < 4; ++q)
        s += fabsf(bflo(uu[q])) + fabsf(bfhi(uu[q]));
    }
    psum[rl][ch] = s;
  }
  __syncthreads();
  if (tid < 64) {
    float s = 0.f;
    #pragma unroll
    for (int j = 0; j < 16; ++j) s += psum[tid][j];
    psum[tid][16] = s;
  }
  __syncthreads();
  if (tid == 0) {
    float mx = 0.f;
    for (int t = 0; t < 64; ++t) mx = fmaxf(mx, psum[t][16]);
    atomicMax(gmax + k, __float_as_uint(mx));   // positive floats: bit order = value order
  }
}

// K5: X1 = 2a*I - a^2 * Pb with a = 2/(1+G)  (closed-form first Newton iterate)
__global__ __launch_bounds__(256) void xinit_kernel(
    const u16* __restrict__ Pb, const unsigned* __restrict__ gmax, u16* __restrict__ X)
{
  const int k = blockIdx.y;
  float lb = __uint_as_float(gmax[k]) * 1.001f + 0.01f;
  if (lb < 1.05f) lb = 1.05f;
  float al = 2.0f / (1.0f + lb);
  float a2 = al * al, two_a = 2.0f * al;
  size_t flat = ((size_t)blockIdx.x * 256 + threadIdx.x) * 8;
  int i = (int)(flat >> 10), j0 = (int)(flat & 1023);
  const size_t mb = (size_t)k * NIND * NIND;
  uint4 u = *(const uint4*)(Pb + mb + flat);
  const unsigned* uu = (const unsigned*)&u;
  unsigned ow[4];
  #pragma unroll
  for (int q = 0; q < 4; ++q) {
    float lo = -a2 * bflo(uu[q]);
    float hi = -a2 * bfhi(uu[q]);
    int cj = j0 + 2 * q;
    if (i == cj) lo += two_a;
    if (i == cj + 1) hi += two_a;
    ow[q] = (f2bf(lo) & 0xFFFFu) | (f2bf(hi) << 16);
  }
  *(uint4*)(X + mb + flat) = uint4{ow[0], ow[1], ow[2], ow[3]};
}

// K6: C = A (*) B^T (all [k][1024][1024] bf16, K-contiguous rows);
// mode 1: C = 2*Xadd - A(*)B^T. 128x128 tile, 4 waves, BK=64, XOR-swizzled LDS.
__global__ __launch_bounds__(256) void ntgemm_kernel(
    const u16* __restrict__ A, const u16* __restrict__ B,
    const u16* __restrict__ Xadd, u16* __restrict__ C, int mode)
{
  __shared__ u16 Als[128 * 64];
  __shared__ u16 Bls[128 * 64];
  const int k = blockIdx.y;
  const int ti = blockIdx.x >> 3, tj = blockIdx.x & 7;
  const int i0 = ti * 128, j0 = tj * 128;
  const int tid = threadIdx.x;
  const int wid = tid >> 6, lane = tid & 63;
  const int wr = wid >> 1, wc = wid & 1;
  const size_t mb = (size_t)k * NIND * NIND;
  const u16* Ag = A + mb + (size_t)i0 * NIND;
  const u16* Bg = B + mb + (size_t)j0 * NIND;
  f32x4 acc[4][4];
  #pragma unroll
  for (int m = 0; m < 4; ++m)
    #pragma unroll
    for (int n = 0; n < 4; ++n) acc[m][n] = (f32x4){0.f, 0.f, 0.f, 0.f};
  for (int kb = 0; kb < NIND; kb += 64) {
    #pragma unroll
    for (int c = 0; c < 4; ++c) {
      int f = c * 256 + tid;
      int row = f >> 3, kc8 = f & 7;
      uint4 va = *(const uint4*)(Ag + (size_t)row * NIND + kb + kc8 * 8);
      uint4 vb = *(const uint4*)(Bg + (size_t)row * NIND + kb + kc8 * 8);
      int idx = (row * 64 + kc8 * 8) ^ ((row & 7) << 3);
      *(uint4*)(&Als[idx]) = va;
      *(uint4*)(&Bls[idx]) = vb;
    }
    __syncthreads();
    #pragma unroll
    for (int ks = 0; ks < 2; ++ks) {
      bf16x8 af[4], bfr[4];
      #pragma unroll
      for (int m = 0; m < 4; ++m) {
        int row = wr * 64 + m * 16 + (lane & 15);
        int kq = ks * 32 + (lane >> 4) * 8;
        int idx = (row * 64 + kq) ^ ((row & 7) << 3);
        af[m] = *(const bf16x8*)(&Als[idx]);
      }
      #pragma unroll
      for (int n = 0; n < 4; ++n) {
        int row = wc * 64 + n * 16 + (lane & 15);
        int kq = ks * 32 + (lane >> 4) * 8;
        int idx = (row * 64 + kq) ^ ((row & 7) << 3);
        bfr[n] = *(const bf16x8*)(&Bls[idx]);
      }
      #pragma unroll
      for (int m = 0; m < 4; ++m)
        #pragma unroll
        for (int n = 0; n < 4; ++n)
          acc[m][n] = __builtin_amdgcn_mfma_f32_16x16x32_bf16(af[m], bfr[n], acc[m][n], 0, 0, 0);
    }
    __syncthreads();
  }
  #pragma unroll
  for (int m = 0; m < 4; ++m) {
    #pragma unroll
    for (int n = 0; n < 4; ++n) {
      #pragma unroll
      for (int r = 0; r < 4; ++r) {
        int gi = i0 + wr * 64 + m * 16 + (lane >> 4) * 4 + r;
        int gj = j0 + wc * 64 + n * 16 + (lane & 15);
        size_t idx = mb + (size_t)gi * NIND + gj;
        float v = acc[m][n][r];
        if (mode) v = 2.0f * bflo((unsigned)Xadd[idx]) - v;
        C[idx] = (u16)f2bf(v);
      }
    }
  }
}

// K7: variance GEMM: C = phi (*) M^T tile; epilogue multiplies by phi[b][i] and
// row-reduces -> partial[itile][k][b]  (var_b = phi^T M phi, M symmetric)
__global__ __launch_bounds__(256) void vgemm_kernel(
    const u16* __restrict__ phiB, const u16* __restrict__ M,
    float* __restrict__ partial)
{
  __shared__ u16 Als[128 * 64];
  __shared__ u16 Bls[128 * 64];
  __shared__ float red[128][33];
  const int btile = blockIdx.x >> 3, It = blockIdx.x & 7;
  const int k = blockIdx.y;
  const int b0 = btile * 128, i0 = It * 128;
  const int tid = threadIdx.x;
  const int wid = tid >> 6, lane = tid & 63;
  const int wr = wid >> 1, wc = wid & 1;
  const int q = lane >> 4, l15 = lane & 15;
  const u16* Ag = phiB + (size_t)b0 * NIND;
  const u16* Bg = M + (size_t)k * NIND * NIND + (size_t)i0 * NIND;
  f32x4 acc[4][4];
  #pragma unroll
  for (int m = 0; m < 4; ++m)
    #pragma unroll
    for (int n = 0; n < 4; ++n) acc[m][n] = (f32x4){0.f, 0.f, 0.f, 0.f};
  for (int kb = 0; kb < NIND; kb += 64) {
    #pragma unroll
    for (int c = 0; c < 4; ++c) {
      int f = c * 256 + tid;
      int row = f >> 3, kc8 = f & 7;
      uint4 va = *(const uint4*)(Ag + (size_t)row * NIND + kb + kc8 * 8);
      uint4 vb = *(const uint4*)(Bg + (size_t)row * NIND + kb + kc8 * 8);
      int idx = (row * 64 + kc8 * 8) ^ ((row & 7) << 3);
      *(uint4*)(&Als[idx]) = va;
      *(uint4*)(&Bls[idx]) = vb;
    }
    __syncthreads();
    #pragma unroll
    for (int ks = 0; ks < 2; ++ks) {
      bf16x8 af[4], bfr[4];
      #pragma unroll
      for (int m = 0; m < 4; ++m) {
        int row = wr * 64 + m * 16 + l15;
        int kq = ks * 32 + q * 8;
        int idx = (row * 64 + kq) ^ ((row & 7) << 3);
        af[m] = *(const bf16x8*)(&Als[idx]);
      }
      #pragma unroll
      for (int n = 0; n < 4; ++n) {
        int row = wc * 64 + n * 16 + l15;
        int kq = ks * 32 + q * 8;
        int idx = (row * 64 + kq) ^ ((row & 7) << 3);
        bfr[n] = *(const bf16x8*)(&Bls[idx]);
      }
      #pragma unroll
      for (int m = 0; m < 4; ++m)
        #pragma unroll
        for (int n = 0; n < 4; ++n)
          acc[m][n] = __builtin_amdgcn_mfma_f32_16x16x32_bf16(af[m], bfr[n], acc[m][n], 0, 0, 0);
    }
    __syncthreads();
  }
  // epilogue: vs[m][r] = sum_n C[gb][gi] * phi[gb][gi]
  float vs[4][4] = {};
  #pragma unroll
  for (int m = 0; m < 4; ++m) {
    #pragma unroll
    for (int r = 0; r < 4; ++r) {
      int gb = b0 + wr * 64 + m * 16 + q * 4 + r;
      #pragma unroll
      for (int n = 0; n < 4; ++n) {
        int gi = i0 + wc * 64 + n * 16 + l15;
        float pv = bflo((unsigned)phiB[(size_t)gb * NIND + gi]);
        vs[m][r] += acc[m][n][r] * pv;
      }
    }
  }
  #pragma unroll
  for (int m = 0; m < 4; ++m)
    #pragma unroll
    for (int r = 0; r < 4; ++r)
      red[wr * 64 + m * 16 + q * 4 + r][wc * 16 + l15] = vs[m][r];
  __syncthreads();
  if (tid < 128) {
    float s = 0.f;
    #pragma unroll
    for (int t = 0; t < 32; ++t) s += red[tid][t];
    partial[((size_t)It * NCLS + k) * BATCH + b0 + tid] = s;
  }
}

// K8: out variances[b][k] = sum_It partial[It][k][b]
__global__ __launch_bounds__(256) void reduce_kernel(
    const float* __restrict__ partial, float* __restrict__ out)
{
  int t = blockIdx.x * 256 + threadIdx.x;
  int k = t >> 11, b = t & 2047;
  float s = 0.f;
  #pragma unroll
  for (int It = 0; It < 8; ++It)
    s += partial[((size_t)It * NCLS + k) * BATCH + b];
  out[(size_t)BATCH * NCLS + (size_t)b * NCLS + k] = s;
}

extern "C" void kernel_launch(void* const* d_in, const int* in_sizes, int n_in,
                              void* d_out, int out_size, void* d_ws, size_t ws_size,
                              hipStream_t stream)
{
  (void)in_sizes; (void)n_in; (void)ws_size;
  const float* x   = (const float*)d_in[0];
  const float* rw  = (const float*)d_in[1];
  const float* rb  = (const float*)d_in[2];
  const float* bw  = (const float*)d_in[3];
  const float* bb  = (const float*)d_in[4];
  const float* prc = (const float*)d_in[5];
  float* out = (float*)d_out;
  char* ws = (char*)d_ws;
  size_t off = 0;
  auto alloc = [&](size_t bytes) -> void* {
    void* p = ws + off;
    off = (off + bytes + 255) & ~(size_t)255;
    return p;
  };
  const size_t MSZ = (size_t)NCLS * NIND * NIND * 2;   // 32MB bf16 matrix
  float* phi    = (float*)alloc((size_t)BATCH * NIND * 4);
  u16*   phiB   = (u16*)  alloc((size_t)BATCH * NIND * 2);
  u16*   phiTB  = (u16*)  alloc((size_t)NIND * BATCH * 2);
  float* sqw    = (float*)alloc((size_t)NCLS * BATCH * 4);
  u16*   Pb     = (u16*)  alloc(MSZ);
  unsigned* gbound = (unsigned*)alloc((size_t)NCLS * 4);
  float* partial = (float*)alloc((size_t)8 * NCLS * BATCH * 4);
  u16*   Xa     = (u16*)alloc(MSZ);
  u16*   B2     = (u16*)alloc(MSZ);
  u16*   BY     = (u16*)alloc(MSZ);
  // total ~145 MB (proven ws >= 193 MB)

  hipMemsetAsync(d_out, 0, (size_t)out_size * sizeof(float), stream);
  hipMemsetAsync(gbound, 0, (size_t)NCLS * 4, stream);
  phi_kernel<<<dim3(BATCH/64, NIND/64), 256, 0, stream>>>(x, rw, rb, phi, phiB, phiTB);
  logits_kernel<<<dim3(BATCH/64), 256, 0, stream>>>(phi, bw, bb, out, sqw);
  gram_kernel<<<dim3(36, NCLS), 256, 0, stream>>>(phiTB, sqw, prc, Pb);
  gersh_kernel<<<dim3(16, NCLS), 256, 0, stream>>>(Pb, gbound);
  xinit_kernel<<<dim3(512, NCLS), 256, 0, stream>>>(Pb, gbound, Xa);
  const dim3 gg(64, NCLS);
  // 4 Newton iterations (X symmetric): YT = X*P ; X' = 2X - X*YT^T
  ntgemm_kernel<<<gg, 256, 0, stream>>>(Xa, Pb, (u16*)nullptr, BY, 0);
  ntgemm_kernel<<<gg, 256, 0, stream>>>(Xa, BY, Xa, B2, 1);
  ntgemm_kernel<<<gg, 256, 0, stream>>>(B2, Pb, (u16*)nullptr, BY, 0);
  ntgemm_kernel<<<gg, 256, 0, stream>>>(B2, BY, B2, Xa, 1);
  ntgemm_kernel<<<gg, 256, 0, stream>>>(Xa, Pb, (u16*)nullptr, BY, 0);
  ntgemm_kernel<<<gg, 256, 0, stream>>>(Xa, BY, Xa, B2, 1);
  ntgemm_kernel<<<gg, 256, 0, stream>>>(B2, Pb, (u16*)nullptr, BY, 0);
  ntgemm_kernel<<<gg, 256, 0, stream>>>(B2, BY, B2, Xa, 1);
  // variances: var_b = phi^T M phi, M = Xa
  vgemm_kernel<<<dim3(128, NCLS), 256, 0, stream>>>(phiB, Xa, partial);
  reduce_kernel<<<dim3(128), 256, 0, stream>>>(partial, out);
}

// Round 10
// 856.715 us; speedup vs baseline: 4.3062x; 1.0809x over previous
//
#include <hip/hip_runtime.h>
#include <hip/hip_bf16.h>

#define BATCH 2048
#define FEAT  768
#define NIND  1024
#define NCLS  16

typedef unsigned short u16;
typedef __attribute__((ext_vector_type(8))) __bf16 bf16x8;
typedef __attribute__((ext_vector_type(4))) float f32x4;

static __device__ __forceinline__ unsigned f2bf(float f) {
  unsigned u = __float_as_uint(f);
  unsigned r = ((u >> 16) & 1u) + 0x7FFFu;
  return (u + r) >> 16;                       // RNE bf16 in low 16 bits
}
static __device__ __forceinline__ float bflo(unsigned x) {
  return __uint_as_float((x & 0xFFFFu) << 16);
}
static __device__ __forceinline__ float bfhi(unsigned x) {
  return __uint_as_float(x & 0xFFFF0000u);
}

// async 16B global->LDS (LDS dest = wave-uniform base + lane*16)
static __device__ __forceinline__ void gload16(const u16* g, u16* l) {
  __builtin_amdgcn_global_load_lds(
      (const __attribute__((address_space(1))) void*)g,
      (__attribute__((address_space(3))) void*)l, 16, 0, 0);
}

// pack 8 bf16 (as uint4) scaled by wv[0..7] back to 8 bf16 (uint4)
static __device__ __forceinline__ uint4 scale8(uint4 v, const float* wv) {
  unsigned out[4];
  const unsigned* in = (const unsigned*)&v;
  #pragma unroll
  for (int i = 0; i < 4; ++i) {
    float lo = bflo(in[i]) * wv[2*i];
    float hi = bfhi(in[i]) * wv[2*i+1];
    __hip_bfloat162 pk = __float22bfloat162_rn(float2{lo, hi});
    out[i] = *(unsigned*)&pk;
  }
  return uint4{out[0], out[1], out[2], out[3]};
}

// K1: phi = sqrt(2/N)*cos(2*(x@W+b)); writes phi [B][N] f32, phiB [B][N] bf16, phiTB [N][B] bf16
__global__ __launch_bounds__(256) void phi_kernel(
    const float* __restrict__ x, const float* __restrict__ rw,
    const float* __restrict__ rb, float* __restrict__ phi,
    u16* __restrict__ phiB, u16* __restrict__ phiTB)
{
  __shared__ float xs[64][17];
  __shared__ float wsh[16][68];
  __shared__ float ts[64][65];
  const int b0 = blockIdx.x * 64, i0 = blockIdx.y * 64;
  const int tid = threadIdx.x;
  const int tr = tid >> 4, tc = tid & 15;
  float acc[4][4] = {};
  for (int k0 = 0; k0 < FEAT; k0 += 16) {
    {
      int bb = tid >> 2, kk = (tid & 3) << 2;
      float4 v = *(const float4*)(x + (size_t)(b0 + bb) * FEAT + k0 + kk);
      xs[bb][kk] = v.x; xs[bb][kk+1] = v.y; xs[bb][kk+2] = v.z; xs[bb][kk+3] = v.w;
      int k2 = tid >> 4, ii = (tid & 15) << 2;
      *(float4*)(&wsh[k2][ii]) = *(const float4*)(rw + (size_t)(k0 + k2) * NIND + i0 + ii);
    }
    __syncthreads();
    #pragma unroll
    for (int q = 0; q < 16; ++q) {
      float a[4];
      #pragma unroll
      for (int r = 0; r < 4; ++r) a[r] = xs[tr*4+r][q];
      float4 b4 = *(const float4*)(&wsh[q][tc*4]);
      float bv[4] = {b4.x, b4.y, b4.z, b4.w};
      #pragma unroll
      for (int r = 0; r < 4; ++r)
        #pragma unroll
        for (int c = 0; c < 4; ++c) acc[r][c] += a[r] * bv[c];
    }
    __syncthreads();
  }
  const float SC = 0.04419417382415922f;   // sqrt(2/1024)
  float4 rb4 = *(const float4*)(rb + i0 + tc*4);
  float rbl[4] = {rb4.x, rb4.y, rb4.z, rb4.w};
  #pragma unroll
  for (int r = 0; r < 4; ++r) {
    float vals[4];
    #pragma unroll
    for (int c = 0; c < 4; ++c) {
      float pr = 2.0f * (acc[r][c] + rbl[c]);
      vals[c] = SC * cosf(pr);
      ts[tr*4+r][tc*4+c] = vals[c];
    }
    float4 o = make_float4(vals[0], vals[1], vals[2], vals[3]);
    *(float4*)(phi + (size_t)(b0 + tr*4 + r) * NIND + i0 + tc*4) = o;
    uint2 ob;
    ob.x = (f2bf(o.x) & 0xFFFFu) | (f2bf(o.y) << 16);
    ob.y = (f2bf(o.z) & 0xFFFFu) | (f2bf(o.w) << 16);
    *(uint2*)(phiB + (size_t)(b0 + tr*4 + r) * NIND + i0 + tc*4) = ob;
  }
  __syncthreads();
  #pragma unroll
  for (int rep = 0; rep < 4; ++rep) {
    int ii = tr*4 + rep;
    int bb2 = tc*4;
    float4 o = make_float4(ts[bb2][ii], ts[bb2+1][ii], ts[bb2+2][ii], ts[bb2+3][ii]);
    uint2 ob;
    ob.x = (f2bf(o.x) & 0xFFFFu) | (f2bf(o.y) << 16);
    ob.y = (f2bf(o.z) & 0xFFFFu) | (f2bf(o.w) << 16);
    *(uint2*)(phiTB + (size_t)(i0 + ii) * BATCH + b0 + bb2) = ob;
  }
}

// K2: tiled logits GEMM + in-block softmax -> wmat[k][b] = p(1-p)
__global__ __launch_bounds__(256) void logits_kernel(
    const float* __restrict__ phi, const float* __restrict__ bw,
    const float* __restrict__ bbias, float* __restrict__ out,
    float* __restrict__ wmat)
{
  __shared__ float ph[64][132];
  __shared__ float bwl[16][132];
  __shared__ float lg[64][17];
  const int b0 = blockIdx.x * 64;
  const int tid = threadIdx.x;
  const int bl = tid & 63, kq = tid >> 6;
  float acc[4] = {};
  for (int kb = 0; kb < NIND; kb += 128) {
    #pragma unroll
    for (int i = 0; i < 8; ++i) {
      int f = i * 256 + tid;
      int row = f >> 5, c4 = (f & 31) << 2;
      *(float4*)(&ph[row][c4]) = *(const float4*)(phi + (size_t)(b0 + row) * NIND + kb + c4);
    }
    #pragma unroll
    for (int i = 0; i < 2; ++i) {
      int f = i * 256 + tid;
      int row = f >> 5, c4 = (f & 31) << 2;
      *(float4*)(&bwl[row][c4]) = *(const float4*)(bw + (size_t)row * NIND + kb + c4);
    }
    __syncthreads();
    #pragma unroll 8
    for (int q = 0; q < 128; q += 4) {
      float4 a = *(const float4*)(&ph[bl][q]);
      #pragma unroll
      for (int j = 0; j < 4; ++j) {
        float4 b4 = *(const float4*)(&bwl[kq*4+j][q]);
        acc[j] += a.x*b4.x + a.y*b4.y + a.z*b4.z + a.w*b4.w;
      }
    }
    __syncthreads();
  }
  #pragma unroll
  for (int j = 0; j < 4; ++j) {
    float v = acc[j] + bbias[kq*4+j];
    lg[bl][kq*4+j] = v;
    out[(size_t)(b0 + bl) * NCLS + kq*4 + j] = v;
  }
  __syncthreads();
  if (tid < 64) {
    float mx = -1e30f;
    #pragma unroll
    for (int k = 0; k < 16; ++k) mx = fmaxf(mx, lg[tid][k]);
    float s = 0.f, ex[16];
    #pragma unroll
    for (int k = 0; k < 16; ++k) { ex[k] = expf(lg[tid][k] - mx); s += ex[k]; }
    float inv = 1.0f / s;
    #pragma unroll
    for (int k = 0; k < 16; ++k) {
      float p = ex[k] * inv;
      wmat[(size_t)k * BATCH + b0 + tid] = p * (1.0f - p);
    }
  }
}

// K3: MFMA bf16 gram -> Pb bf16. A = (w*phi) via reg-staging; B = raw phi via gload_lds.
__global__ __launch_bounds__(256) void gram_kernel(
    const u16* __restrict__ phiTB, const float* __restrict__ wmat,
    const float* __restrict__ prec, u16* __restrict__ Pb)
{
  __shared__ u16 Als[128 * 64];
  __shared__ u16 Bls[128 * 64];
  int p = blockIdx.x;
  int ti = 0;
  while ((ti + 1) * (ti + 2) / 2 <= p) ++ti;
  int tj = p - ti * (ti + 1) / 2;
  const int k = blockIdx.y;
  const int i0 = ti * 128, j0 = tj * 128;
  const bool diag = (ti == tj);
  const int tid = threadIdx.x;
  const int wid = tid >> 6, lane = tid & 63;
  const int wr = wid >> 1, wc = wid & 1;
  const u16* Ag = phiTB + (size_t)i0 * BATCH;
  const u16* Bg = phiTB + (size_t)j0 * BATCH;
  const float* sw = wmat + (size_t)k * BATCH;
  f32x4 acc[4][4];
  #pragma unroll
  for (int m = 0; m < 4; ++m)
    #pragma unroll
    for (int n = 0; n < 4; ++n) acc[m][n] = (f32x4){0.f, 0.f, 0.f, 0.f};
  const int kc8 = tid & 7;
  for (int b0 = 0; b0 < BATCH; b0 += 64) {
    // B raw, async gload_lds with pre-swizzled source
    #pragma unroll
    for (int c = 0; c < 4; ++c) {
      int f = c * 256 + tid;
      int row = f >> 3, s = f & 7;
      int sc = (s ^ (row & 7)) << 3;
      gload16(Bg + (size_t)row * BATCH + b0 + sc, Bls + ((c * 256 + wid * 64) << 3));
    }
    // A scaled by w (reg path)
    const int bcol = b0 + kc8 * 8;
    float4 w0 = *(const float4*)(sw + bcol);
    float4 w1 = *(const float4*)(sw + bcol + 4);
    float wv[8] = {w0.x, w0.y, w0.z, w0.w, w1.x, w1.y, w1.z, w1.w};
    #pragma unroll
    for (int c = 0; c < 4; ++c) {
      int row = c * 32 + (tid >> 3);
      int idx = (row * 64 + kc8 * 8) ^ ((row & 7) << 3);
      uint4 va = *(const uint4*)(Ag + (size_t)row * BATCH + bcol);
      *(uint4*)(&Als[idx]) = scale8(va, wv);
    }
    __syncthreads();
    #pragma unroll
    for (int ks = 0; ks < 2; ++ks) {
      bf16x8 af[4], bfr[4];
      #pragma unroll
      for (int m = 0; m < 4; ++m) {
        int row = wr * 64 + m * 16 + (lane & 15);
        int kb = ks * 32 + (lane >> 4) * 8;
        int idx = (row * 64 + kb) ^ ((row & 7) << 3);
        af[m] = *(const bf16x8*)(&Als[idx]);
      }
      #pragma unroll
      for (int n = 0; n < 4; ++n) {
        int row = wc * 64 + n * 16 + (lane & 15);
        int kb = ks * 32 + (lane >> 4) * 8;
        int idx = (row * 64 + kb) ^ ((row & 7) << 3);
        bfr[n] = *(const bf16x8*)(&Bls[idx]);
      }
      #pragma unroll
      for (int m = 0; m < 4; ++m)
        #pragma unroll
        for (int n = 0; n < 4; ++n)
          acc[m][n] = __builtin_amdgcn_mfma_f32_16x16x32_bf16(af[m], bfr[n], acc[m][n], 0, 0, 0);
    }
    __syncthreads();
  }
  const size_t kb2 = (size_t)k * NIND * NIND;
  #pragma unroll
  for (int m = 0; m < 4; ++m) {
    #pragma unroll
    for (int n = 0; n < 4; ++n) {
      #pragma unroll
      for (int r = 0; r < 4; ++r) {
        int gi = i0 + wr * 64 + m * 16 + (lane >> 4) * 4 + r;
        int gj = j0 + wc * 64 + n * 16 + (lane & 15);
        size_t idx = kb2 + (size_t)gi * NIND + gj;
        float v = acc[m][n][r] + prec[idx];
        u16 bv = (u16)f2bf(v);
        Pb[idx] = bv;
        if (!diag) Pb[kb2 + (size_t)gj * NIND + gi] = bv;
      }
    }
  }
}

// K4: Gershgorin bound per class: gmax[k] = max_i sum_j |P_ij| (certified >= lambda_max)
__global__ __launch_bounds__(256) void gersh_kernel(
    const u16* __restrict__ Pb, unsigned* __restrict__ gmax)
{
  __shared__ float psum[64][17];
  const int k = blockIdx.y, rbk = blockIdx.x;
  const int tid = threadIdx.x;
  const size_t mb = (size_t)k * NIND * NIND;
  #pragma unroll
  for (int p = 0; p < 4; ++p) {
    int rl = p * 16 + (tid >> 4);
    int row = rbk * 64 + rl;
    int ch = tid & 15;
    float s = 0.f;
    const u16* base = Pb + mb + (size_t)row * NIND + ch * 64;
    #pragma unroll
    for (int c8 = 0; c8 < 8; ++c8) {
      uint4 u = *(const uint4*)(base + c8 * 8);
      const unsigned* uu = (const unsigned*)&u;
      #pragma unroll
      for (int q = 0; q < 4; ++q)
        s += fabsf(bflo(uu[q])) + fabsf(bfhi(uu[q]));
    }
    psum[rl][ch] = s;
  }
  __syncthreads();
  if (tid < 64) {
    float s = 0.f;
    #pragma unroll
    for (int j = 0; j < 16; ++j) s += psum[tid][j];
    psum[tid][16] = s;
  }
  __syncthreads();
  if (tid == 0) {
    float mx = 0.f;
    for (int t = 0; t < 64; ++t) mx = fmaxf(mx, psum[t][16]);
    atomicMax(gmax + k, __float_as_uint(mx));
  }
}

// K5: X1 = 2a*I - a^2 * Pb with a = 2/(1+G)
__global__ __launch_bounds__(256) void xinit_kernel(
    const u16* __restrict__ Pb, const unsigned* __restrict__ gmax, u16* __restrict__ X)
{
  const int k = blockIdx.y;
  float lb = __uint_as_float(gmax[k]) * 1.001f + 0.01f;
  if (lb < 1.05f) lb = 1.05f;
  float al = 2.0f / (1.0f + lb);
  float a2 = al * al, two_a = 2.0f * al;
  size_t flat = ((size_t)blockIdx.x * 256 + threadIdx.x) * 8;
  int i = (int)(flat >> 10), j0 = (int)(flat & 1023);
  const size_t mb = (size_t)k * NIND * NIND;
  uint4 u = *(const uint4*)(Pb + mb + flat);
  const unsigned* uu = (const unsigned*)&u;
  unsigned ow[4];
  #pragma unroll
  for (int q = 0; q < 4; ++q) {
    float lo = -a2 * bflo(uu[q]);
    float hi = -a2 * bfhi(uu[q]);
    int cj = j0 + 2 * q;
    if (i == cj) lo += two_a;
    if (i == cj + 1) hi += two_a;
    ow[q] = (f2bf(lo) & 0xFFFFu) | (f2bf(hi) << 16);
  }
  *(uint4*)(X + mb + flat) = uint4{ow[0], ow[1], ow[2], ow[3]};
}

// K6: C = A (*) B^T; mode 1: C = 2*Xadd - A(*)B^T. Both operands via gload_lds.
__global__ __launch_bounds__(256) void ntgemm_kernel(
    const u16* __restrict__ A, const u16* __restrict__ B,
    const u16* __restrict__ Xadd, u16* __restrict__ C, int mode)
{
  __shared__ u16 Als[128 * 64];
  __shared__ u16 Bls[128 * 64];
  const int k = blockIdx.y;
  const int ti = blockIdx.x >> 3, tj = blockIdx.x & 7;
  const int i0 = ti * 128, j0 = tj * 128;
  const int tid = threadIdx.x;
  const int wid = tid >> 6, lane = tid & 63;
  const int wr = wid >> 1, wc = wid & 1;
  const size_t mb = (size_t)k * NIND * NIND;
  const u16* Ag = A + mb + (size_t)i0 * NIND;
  const u16* Bg = B + mb + (size_t)j0 * NIND;
  f32x4 acc[4][4];
  #pragma unroll
  for (int m = 0; m < 4; ++m)
    #pragma unroll
    for (int n = 0; n < 4; ++n) acc[m][n] = (f32x4){0.f, 0.f, 0.f, 0.f};
  for (int kb = 0; kb < NIND; kb += 64) {
    #pragma unroll
    for (int c = 0; c < 4; ++c) {
      int f = c * 256 + tid;
      int row = f >> 3, s = f & 7;
      int sc = (s ^ (row & 7)) << 3;
      gload16(Ag + (size_t)row * NIND + kb + sc, Als + ((c * 256 + wid * 64) << 3));
      gload16(Bg + (size_t)row * NIND + kb + sc, Bls + ((c * 256 + wid * 64) << 3));
    }
    __syncthreads();
    #pragma unroll
    for (int ks = 0; ks < 2; ++ks) {
      bf16x8 af[4], bfr[4];
      #pragma unroll
      for (int m = 0; m < 4; ++m) {
        int row = wr * 64 + m * 16 + (lane & 15);
        int kq = ks * 32 + (lane >> 4) * 8;
        int idx = (row * 64 + kq) ^ ((row & 7) << 3);
        af[m] = *(const bf16x8*)(&Als[idx]);
      }
      #pragma unroll
      for (int n = 0; n < 4; ++n) {
        int row = wc * 64 + n * 16 + (lane & 15);
        int kq = ks * 32 + (lane >> 4) * 8;
        int idx = (row * 64 + kq) ^ ((row & 7) << 3);
        bfr[n] = *(const bf16x8*)(&Bls[idx]);
      }
      #pragma unroll
      for (int m = 0; m < 4; ++m)
        #pragma unroll
        for (int n = 0; n < 4; ++n)
          acc[m][n] = __builtin_amdgcn_mfma_f32_16x16x32_bf16(af[m], bfr[n], acc[m][n], 0, 0, 0);
    }
    __syncthreads();
  }
  #pragma unroll
  for (int m = 0; m < 4; ++m) {
    #pragma unroll
    for (int n = 0; n < 4; ++n) {
      #pragma unroll
      for (int r = 0; r < 4; ++r) {
        int gi = i0 + wr * 64 + m * 16 + (lane >> 4) * 4 + r;
        int gj = j0 + wc * 64 + n * 16 + (lane & 15);
        size_t idx = mb + (size_t)gi * NIND + gj;
        float v = acc[m][n][r];
        if (mode) v = 2.0f * bflo((unsigned)Xadd[idx]) - v;
        C[idx] = (u16)f2bf(v);
      }
    }
  }
}

// K7: variance GEMM: C = phi (*) M^T; epilogue * phi[b][i], row-reduce -> partial
__global__ __launch_bounds__(256) void vgemm_kernel(
    const u16* __restrict__ phiB, const u16* __restrict__ M,
    float* __restrict__ partial)
{
  __shared__ u16 Als[128 * 64];
  __shared__ u16 Bls[128 * 64];
  __shared__ float red[128][33];
  const int btile = blockIdx.x >> 3, It = blockIdx.x & 7;
  const int k = blockIdx.y;
  const int b0 = btile * 128, i0 = It * 128;
  const int tid = threadIdx.x;
  const int wid = tid >> 6, lane = tid & 63;
  const int wr = wid >> 1, wc = wid & 1;
  const int q = lane >> 4, l15 = lane & 15;
  const u16* Ag = phiB + (size_t)b0 * NIND;
  const u16* Bg = M + (size_t)k * NIND * NIND + (size_t)i0 * NIND;
  f32x4 acc[4][4];
  #pragma unroll
  for (int m = 0; m < 4; ++m)
    #pragma unroll
    for (int n = 0; n < 4; ++n) acc[m][n] = (f32x4){0.f, 0.f, 0.f, 0.f};
  for (int kb = 0; kb < NIND; kb += 64) {
    #pragma unroll
    for (int c = 0; c < 4; ++c) {
      int f = c * 256 + tid;
      int row = f >> 3, s = f & 7;
      int sc = (s ^ (row & 7)) << 3;
      gload16(Ag + (size_t)row * NIND + kb + sc, Als + ((c * 256 + wid * 64) << 3));
      gload16(Bg + (size_t)row * NIND + kb + sc, Bls + ((c * 256 + wid * 64) << 3));
    }
    __syncthreads();
    #pragma unroll
    for (int ks = 0; ks < 2; ++ks) {
      bf16x8 af[4], bfr[4];
      #pragma unroll
      for (int m = 0; m < 4; ++m) {
        int row = wr * 64 + m * 16 + l15;
        int kq = ks * 32 + q * 8;
        int idx = (row * 64 + kq) ^ ((row & 7) << 3);
        af[m] = *(const bf16x8*)(&Als[idx]);
      }
      #pragma unroll
      for (int n = 0; n < 4; ++n) {
        int row = wc * 64 + n * 16 + l15;
        int kq = ks * 32 + q * 8;
        int idx = (row * 64 + kq) ^ ((row & 7) << 3);
        bfr[n] = *(const bf16x8*)(&Bls[idx]);
      }
      #pragma unroll
      for (int m = 0; m < 4; ++m)
        #pragma unroll
        for (int n = 0; n < 4; ++n)
          acc[m][n] = __builtin_amdgcn_mfma_f32_16x16x32_bf16(af[m], bfr[n], acc[m][n], 0, 0, 0);
    }
    __syncthreads();
  }
  float vs[4][4] = {};
  #pragma unroll
  for (int m = 0; m < 4; ++m) {
    #pragma unroll
    for (int r = 0; r < 4; ++r) {
      int gb = b0 + wr * 64 + m * 16 + q * 4 + r;
      #pragma unroll
      for (int n = 0; n < 4; ++n) {
        int gi = i0 + wc * 64 + n * 16 + l15;
        float pv = bflo((unsigned)phiB[(size_t)gb * NIND + gi]);
        vs[m][r] += acc[m][n][r] * pv;
      }
    }
  }
  #pragma unroll
  for (int m = 0; m < 4; ++m)
    #pragma unroll
    for (int r = 0; r < 4; ++r)
      red[wr * 64 + m * 16 + q * 4 + r][wc * 16 + l15] = vs[m][r];
  __syncthreads();
  if (tid < 128) {
    float s = 0.f;
    #pragma unroll
    for (int t = 0; t < 32; ++t) s += red[tid][t];
    partial[((size_t)It * NCLS + k) * BATCH + b0 + tid] = s;
  }
}

// K8: out variances[b][k] = sum_It partial[It][k][b]
__global__ __launch_bounds__(256) void reduce_kernel(
    const float* __restrict__ partial, float* __restrict__ out)
{
  int t = blockIdx.x * 256 + threadIdx.x;
  int k = t >> 11, b = t & 2047;
  float s = 0.f;
  #pragma unroll
  for (int It = 0; It < 8; ++It)
    s += partial[((size_t)It * NCLS + k) * BATCH + b];
  out[(size_t)BATCH * NCLS + (size_t)b * NCLS + k] = s;
}

extern "C" void kernel_launch(void* const* d_in, const int* in_sizes, int n_in,
                              void* d_out, int out_size, void* d_ws, size_t ws_size,
                              hipStream_t stream)
{
  (void)in_sizes; (void)n_in; (void)ws_size;
  const float* x   = (const float*)d_in[0];
  const float* rw  = (const float*)d_in[1];
  const float* rb  = (const float*)d_in[2];
  const float* bw  = (const float*)d_in[3];
  const float* bb  = (const float*)d_in[4];
  const float* prc = (const float*)d_in[5];
  float* out = (float*)d_out;
  char* ws = (char*)d_ws;
  size_t off = 0;
  auto alloc = [&](size_t bytes) -> void* {
    void* p = ws + off;
    off = (off + bytes + 255) & ~(size_t)255;
    return p;
  };
  const size_t MSZ = (size_t)NCLS * NIND * NIND * 2;   // 32MB bf16 matrix
  float* phi    = (float*)alloc((size_t)BATCH * NIND * 4);
  u16*   phiB   = (u16*)  alloc((size_t)BATCH * NIND * 2);
  u16*   phiTB  = (u16*)  alloc((size_t)NIND * BATCH * 2);
  float* wmat   = (float*)alloc((size_t)NCLS * BATCH * 4);
  u16*   Pb     = (u16*)  alloc(MSZ);
  unsigned* gbound = (unsigned*)alloc((size_t)NCLS * 4);
  float* partial = (float*)alloc((size_t)8 * NCLS * BATCH * 4);
  u16*   Xa     = (u16*)alloc(MSZ);
  u16*   B2     = (u16*)alloc(MSZ);
  u16*   BY     = (u16*)alloc(MSZ);

  hipMemsetAsync(d_out, 0, (size_t)out_size * sizeof(float), stream);
  hipMemsetAsync(gbound, 0, (size_t)NCLS * 4, stream);
  phi_kernel<<<dim3(BATCH/64, NIND/64), 256, 0, stream>>>(x, rw, rb, phi, phiB, phiTB);
  logits_kernel<<<dim3(BATCH/64), 256, 0, stream>>>(phi, bw, bb, out, wmat);
  gram_kernel<<<dim3(36, NCLS), 256, 0, stream>>>(phiTB, wmat, prc, Pb);
  gersh_kernel<<<dim3(16, NCLS), 256, 0, stream>>>(Pb, gbound);
  xinit_kernel<<<dim3(512, NCLS), 256, 0, stream>>>(Pb, gbound, Xa);
  const dim3 gg(64, NCLS);
  // 4 Newton iterations (X symmetric): YT = X*P ; X' = 2X - X*YT^T
  ntgemm_kernel<<<gg, 256, 0, stream>>>(Xa, Pb, (u16*)nullptr, BY, 0);
  ntgemm_kernel<<<gg, 256, 0, stream>>>(Xa, BY, Xa, B2, 1);
  ntgemm_kernel<<<gg, 256, 0, stream>>>(B2, Pb, (u16*)nullptr, BY, 0);
  ntgemm_kernel<<<gg, 256, 0, stream>>>(B2, BY, B2, Xa, 1);
  ntgemm_kernel<<<gg, 256, 0, stream>>>(Xa, Pb, (u16*)nullptr, BY, 0);
  ntgemm_kernel<<<gg, 256, 0, stream>>>(Xa, BY, Xa, B2, 1);
  ntgemm_kernel<<<gg, 256, 0, stream>>>(B2, Pb, (u16*)nullptr, BY, 0);
  ntgemm_kernel<<<gg, 256, 0, stream>>>(B2, BY, B2, Xa, 1);
  // variances: var_b = phi^T M phi, M = Xa
  vgemm_kernel<<<dim3(128, NCLS), 256, 0, stream>>>(phiB, Xa, partial);
  reduce_kernel<<<dim3(128), 256, 0, stream>>>(partial, out);
}